// Round 2
// baseline (930.945 us; speedup 1.0000x reference)
//
#include <hip/hip_runtime.h>

#define NN 50000
#define ICH 256
#define HID 64
#define HEADS 4
#define OCH 40
#define NE 800000
#define ETOT (NE + NN)
#define SLOPE 0.2f

// ---------------- GEMM: C[M,N] = A[M,K] @ B[K,N], fp32 ---------------------
template <int BM, int BN, int BK>
__global__ void gemm_f32(const float* __restrict__ A, const float* __restrict__ B,
                         float* __restrict__ C, int M, int K, int N) {
    __shared__ float As[BK][BM + 1];
    __shared__ float Bs[BK][BN + 1];
    int tid = threadIdx.x;             // 256 threads
    int tx = tid & 15, ty = tid >> 4;  // 16x16
    int row0 = blockIdx.y * BM;
    int col0 = blockIdx.x * BN;
    float acc[4][4] = {};
    for (int k0 = 0; k0 < K; k0 += BK) {
        for (int i = tid; i < BM * BK; i += 256) {
            int r = i / BK, c = i % BK;
            int gr = row0 + r;
            As[c][r] = (gr < M) ? A[(size_t)gr * K + k0 + c] : 0.f;
        }
        for (int i = tid; i < BK * BN; i += 256) {
            int r = i / BN, c = i % BN;
            int gc = col0 + c;
            Bs[r][c] = (gc < N) ? B[(size_t)(k0 + r) * N + gc] : 0.f;
        }
        __syncthreads();
        for (int kk = 0; kk < BK; ++kk) {
            float a[4], b[4];
#pragma unroll
            for (int i = 0; i < 4; i++) a[i] = As[kk][ty * 4 + i];
#pragma unroll
            for (int j = 0; j < 4; j++) b[j] = Bs[kk][tx * 4 + j];
#pragma unroll
            for (int i = 0; i < 4; i++)
#pragma unroll
                for (int j = 0; j < 4; j++) acc[i][j] += a[i] * b[j];
        }
        __syncthreads();
    }
#pragma unroll
    for (int i = 0; i < 4; i++) {
        int gr = row0 + ty * 4 + i;
        if (gr >= M) continue;
#pragma unroll
        for (int j = 0; j < 4; j++) {
            int gc = col0 + tx * 4 + j;
            if (gc < N) C[(size_t)gr * N + gc] = acc[i][j];
        }
    }
}

// ------------- per-node attention logits: al = sum_c h[n,head,c]*a[head,c] ---
__global__ void al_kernel(const float* __restrict__ h, const float* __restrict__ a_s,
                          const float* __restrict__ a_d, float* __restrict__ alsrc,
                          float* __restrict__ aldst, int n, int heads, int HC) {
    int t = threadIdx.x;
    int head = t >> 6, lane = t & 63;
    bool on = lane < HC;
    int CH = heads * HC;
    int c = head * HC + lane;
    float as = on ? a_s[c] : 0.f;
    float ad = on ? a_d[c] : 0.f;
    for (int node = blockIdx.x; node < n; node += gridDim.x) {
        float hv = on ? h[(size_t)node * CH + c] : 0.f;
        float vs = hv * as, vd = hv * ad;
#pragma unroll
        for (int off = 32; off > 0; off >>= 1) {
            vs += __shfl_down(vs, off, 64);
            vd += __shfl_down(vd, off, 64);
        }
        if (lane == 0) {
            alsrc[node * heads + head] = vs;
            aldst[node * heads + head] = vd;
        }
    }
}

// ---------------- CSR build ----------------
__global__ void hist_kernel(const int* __restrict__ dstArr, int* __restrict__ deg) {
    int i = blockIdx.x * blockDim.x + threadIdx.x;
    if (i < ETOT) {
        int d = (i < NE) ? dstArr[i] : (i - NE);
        atomicAdd(&deg[d], 1);
    }
}

__global__ void scan_kernel(const int* __restrict__ deg, int* __restrict__ offs,
                            int* __restrict__ cur, int n) {
    __shared__ int part[1024];
    int t = threadIdx.x;
    int chunk = (n + 1023) / 1024;
    int base = t * chunk;
    int s = 0;
    for (int i = 0; i < chunk; i++) {
        int idx = base + i;
        if (idx < n) s += deg[idx];
    }
    part[t] = s;
    __syncthreads();
    for (int d = 1; d < 1024; d <<= 1) {
        int v = (t >= d) ? part[t - d] : 0;
        __syncthreads();
        part[t] += v;
        __syncthreads();
    }
    int prefix = (t == 0) ? 0 : part[t - 1];
    for (int i = 0; i < chunk; i++) {
        int idx = base + i;
        if (idx < n) {
            offs[idx] = prefix;
            cur[idx] = prefix;
            prefix += deg[idx];
        }
    }
    if (t == 1023) offs[n] = part[1023];
}

__global__ void scatter_kernel(const int* __restrict__ srcArr, const int* __restrict__ dstArr,
                               int* __restrict__ cur, int* __restrict__ csr) {
    int i = blockIdx.x * blockDim.x + threadIdx.x;
    if (i < ETOT) {
        int s, d;
        if (i < NE) {
            s = srcArr[i];
            d = dstArr[i];
        } else {
            s = d = i - NE;
        }
        int pos = atomicAdd(&cur[d], 1);
        csr[pos] = s;
    }
}

// ---------------- layer-1 aggregation: softmax-weighted mean + bias + ELU ---
__global__ void aggregate1(const int* __restrict__ offs, const int* __restrict__ csr,
                           const float* __restrict__ h, const float* __restrict__ alsrc,
                           const float* __restrict__ aldst, const float* __restrict__ bias,
                           float* __restrict__ z) {
    int d = blockIdx.x;
    int c = threadIdx.x;  // 0..255
    int head = c >> 6;
    int e0 = offs[d], e1 = offs[d + 1];
    float ald = aldst[d * HEADS + head];
    float acc = 0.f, wsum = 0.f;
    for (int e = e0; e < e1; ++e) {
        int s = csr[e];
        float x = alsrc[s * HEADS + head] + ald;
        x = (x > 0.f) ? x : SLOPE * x;
        float w = __expf(x);
        wsum += w;
        acc += w * h[(size_t)s * ICH + c];
    }
    float o = acc / (wsum + 1e-16f) + bias[c];
    o = (o > 0.f) ? o : (__expf(o) - 1.f);  // ELU
    z[(size_t)d * ICH + c] = o;
}

// ---------------- layer-2 aggregation: 1 head, 40 ch, + bias, write output ---
__global__ void aggregate2(const int* __restrict__ offs, const int* __restrict__ csr,
                           const float* __restrict__ h2, const float* __restrict__ alsrc,
                           const float* __restrict__ aldst, const float* __restrict__ bias,
                           float* __restrict__ out, int n) {
    int nl = threadIdx.x >> 6;
    int c = threadIdx.x & 63;
    int d = blockIdx.x * 4 + nl;
    if (d >= n) return;
    bool on = c < OCH;
    int e0 = offs[d], e1 = offs[d + 1];
    float ald = aldst[d];
    float acc = 0.f, wsum = 0.f;
    for (int e = e0; e < e1; ++e) {
        int s = csr[e];
        float x = alsrc[s] + ald;
        x = (x > 0.f) ? x : SLOPE * x;
        float w = __expf(x);
        wsum += w;
        if (on) acc += w * h2[(size_t)s * OCH + c];
    }
    if (on) out[(size_t)d * OCH + c] = acc / (wsum + 1e-16f) + bias[c];
}

extern "C" void kernel_launch(void* const* d_in, const int* in_sizes, int n_in,
                              void* d_out, int out_size, void* d_ws, size_t ws_size,
                              hipStream_t stream) {
    const float* x   = (const float*)d_in[0];
    const int*   ei  = (const int*)d_in[1];
    const float* W1  = (const float*)d_in[2];
    const float* as1 = (const float*)d_in[3];
    const float* ad1 = (const float*)d_in[4];
    const float* b1  = (const float*)d_in[5];
    const float* W2  = (const float*)d_in[6];
    const float* as2 = (const float*)d_in[7];
    const float* ad2 = (const float*)d_in[8];
    const float* b2  = (const float*)d_in[9];
    float* out = (float*)d_out;

    char* ws = (char*)d_ws;
    size_t o = 0;
    auto alloc = [&](size_t bytes) {
        void* p = ws + o;
        o += (bytes + 255) & ~(size_t)255;
        return p;
    };
    float* h1     = (float*)alloc((size_t)NN * ICH * 4);
    float* z      = (float*)alloc((size_t)NN * ICH * 4);
    float* h2     = (float*)alloc((size_t)NN * OCH * 4);
    float* alsrc1 = (float*)alloc((size_t)NN * HEADS * 4);
    float* aldst1 = (float*)alloc((size_t)NN * HEADS * 4);
    float* alsrc2 = (float*)alloc((size_t)NN * 4);
    float* aldst2 = (float*)alloc((size_t)NN * 4);
    int*   deg    = (int*)alloc((size_t)NN * 4);
    int*   offs   = (int*)alloc((size_t)(NN + 1) * 4);
    int*   cur    = (int*)alloc((size_t)NN * 4);
    int*   csr    = (int*)alloc((size_t)ETOT * 4);

    const int* srcArr = ei;
    const int* dstArr = ei + NE;

    // CSR build (graph shared by both layers)
    hipMemsetAsync(deg, 0, (size_t)NN * 4, stream);
    hist_kernel<<<(ETOT + 255) / 256, 256, 0, stream>>>(dstArr, deg);
    scan_kernel<<<1, 1024, 0, stream>>>(deg, offs, cur, NN);
    scatter_kernel<<<(ETOT + 255) / 256, 256, 0, stream>>>(srcArr, dstArr, cur, csr);

    // Layer 1
    gemm_f32<64, 64, 32><<<dim3(4, (NN + 63) / 64), 256, 0, stream>>>(x, W1, h1, NN, ICH, HEADS * HID);
    al_kernel<<<4096, 256, 0, stream>>>(h1, as1, ad1, alsrc1, aldst1, NN, HEADS, HID);
    aggregate1<<<NN, 256, 0, stream>>>(offs, csr, h1, alsrc1, aldst1, b1, z);

    // Layer 2
    gemm_f32<64, 64, 32><<<dim3(1, (NN + 63) / 64), 256, 0, stream>>>(z, W2, h2, NN, HEADS * HID, OCH);
    al_kernel<<<4096, 64, 0, stream>>>(h2, as2, ad2, alsrc2, aldst2, NN, 1, OCH);
    aggregate2<<<(NN + 3) / 4, 256, 0, stream>>>(offs, csr, h2, alsrc2, aldst2, b2, out, NN);
}

// Round 3
// 685.532 us; speedup vs baseline: 1.3580x; 1.3580x over previous
//
#include <hip/hip_runtime.h>

#define NN 50000
#define MPAD 50048   // 391 * 128
#define ICH 256
#define HID 64
#define HEADS 4
#define OCH 40
#define NE 800000
#define ETOT (NE + NN)
#define SLOPE 0.2f
#define LDP 40  // padded LDS row stride (bf16 elems): 32 data + 8 pad

typedef __bf16 v8bf __attribute__((ext_vector_type(8)));
typedef float v4f __attribute__((ext_vector_type(4)));

// ---------------- fp32 -> bf16 conversion (vectorized) ----------------
__global__ void conv_bf16(const float* __restrict__ in, __bf16* __restrict__ out, int n4) {
    int i = blockIdx.x * blockDim.x + threadIdx.x;
    if (i < n4) {
        float4 v = ((const float4*)in)[i];
        union { __bf16 h[4]; uint2 u; } p;
        p.h[0] = (__bf16)v.x; p.h[1] = (__bf16)v.y;
        p.h[2] = (__bf16)v.z; p.h[3] = (__bf16)v.w;
        ((uint2*)out)[i] = p.u;
    }
}

// W1 [K=256][N=256] fp32 -> W1T [256][256] bf16
__global__ void transW1(const float* __restrict__ W, __bf16* __restrict__ WT) {
    int i = blockIdx.x * blockDim.x + threadIdx.x;  // 65536
    int n = i >> 8, k = i & 255;
    WT[n * 256 + k] = (__bf16)W[k * 256 + n];
}

// W2 [256][40] fp32 -> W2T [128][256] bf16 (zero-padded cols 40..127)
__global__ void transW2(const float* __restrict__ W, __bf16* __restrict__ WT) {
    int i = blockIdx.x * blockDim.x + threadIdx.x;  // 32768
    int n = i >> 8, k = i & 255;
    WT[n * 256 + k] = (n < OCH) ? (__bf16)W[k * OCH + n] : (__bf16)0.f;
}

// ---------------- MFMA GEMM: C[M,128*gx] = A[M,256] @ B^T, bf16 -----------
// A: [MPAD][256] bf16, B: B^T [>=128*gx][256] bf16, C: [MPAD][ldc] bf16
__global__ __launch_bounds__(256) void gemm_mfma(const __bf16* __restrict__ A,
                                                 const __bf16* __restrict__ B,
                                                 __bf16* __restrict__ C, int ldc) {
    __shared__ __bf16 As[128 * LDP];
    __shared__ __bf16 Bs[128 * LDP];
    int tid = threadIdx.x;
    int lane = tid & 63, wid = tid >> 6;
    int quad = lane >> 4, l15 = lane & 15;
    int wm = (wid & 1) * 64, wn = (wid >> 1) * 64;
    long row0 = (long)blockIdx.y * 128;
    long col0 = (long)blockIdx.x * 128;
    v4f acc[4][4] = {};
    for (int k0 = 0; k0 < 256; k0 += 32) {
#pragma unroll
        for (int i = tid; i < 512; i += 256) {
            int r = i >> 2, q = i & 3;
            *(uint4*)(&As[r * LDP + q * 8]) = *(const uint4*)(A + (row0 + r) * 256 + k0 + q * 8);
            *(uint4*)(&Bs[r * LDP + q * 8]) = *(const uint4*)(B + (col0 + r) * 256 + k0 + q * 8);
        }
        __syncthreads();
        v8bf af[4], bfr[4];
#pragma unroll
        for (int t = 0; t < 4; t++) {
            af[t]  = *(const v8bf*)(&As[(wm + t * 16 + l15) * LDP + quad * 8]);
            bfr[t] = *(const v8bf*)(&Bs[(wn + t * 16 + l15) * LDP + quad * 8]);
        }
#pragma unroll
        for (int mi = 0; mi < 4; mi++)
#pragma unroll
            for (int ni = 0; ni < 4; ni++)
                acc[mi][ni] = __builtin_amdgcn_mfma_f32_16x16x32_bf16(af[mi], bfr[ni], acc[mi][ni], 0, 0, 0);
        __syncthreads();
    }
#pragma unroll
    for (int mi = 0; mi < 4; mi++)
#pragma unroll
        for (int ni = 0; ni < 4; ni++)
#pragma unroll
            for (int r = 0; r < 4; r++) {
                long row = row0 + wm + mi * 16 + quad * 4 + r;
                long col = col0 + wn + ni * 16 + l15;
                C[row * ldc + col] = (__bf16)acc[mi][ni][r];
            }
}

// ------------- per-node attention logits ----------------------------------
__global__ void al_kernel(const __bf16* __restrict__ h, const float* __restrict__ a_s,
                          const float* __restrict__ a_d, float* __restrict__ alsrc,
                          float* __restrict__ aldst, int n, int heads, int HC, int rowstride) {
    int t = threadIdx.x;
    int head = t >> 6, lane = t & 63;
    bool on = lane < HC;
    int c = head * HC + lane;
    float as = on ? a_s[c] : 0.f;
    float ad = on ? a_d[c] : 0.f;
    for (int node = blockIdx.x; node < n; node += gridDim.x) {
        float hv = on ? (float)h[(size_t)node * rowstride + c] : 0.f;
        float vs = hv * as, vd = hv * ad;
#pragma unroll
        for (int off = 32; off > 0; off >>= 1) {
            vs += __shfl_down(vs, off, 64);
            vd += __shfl_down(vd, off, 64);
        }
        if (lane == 0) {
            alsrc[node * heads + head] = vs;
            aldst[node * heads + head] = vd;
        }
    }
}

// ---------------- CSR build ----------------
__global__ void hist_kernel(const int* __restrict__ dstArr, int* __restrict__ deg) {
    int i = blockIdx.x * blockDim.x + threadIdx.x;
    if (i < ETOT) {
        int d = (i < NE) ? dstArr[i] : (i - NE);
        atomicAdd(&deg[d], 1);
    }
}

__global__ void scan_kernel(const int* __restrict__ deg, int* __restrict__ offs,
                            int* __restrict__ cur, int n) {
    __shared__ int part[1024];
    int t = threadIdx.x;
    int chunk = (n + 1023) / 1024;
    int base = t * chunk;
    int s = 0;
    for (int i = 0; i < chunk; i++) {
        int idx = base + i;
        if (idx < n) s += deg[idx];
    }
    part[t] = s;
    __syncthreads();
    for (int d = 1; d < 1024; d <<= 1) {
        int v = (t >= d) ? part[t - d] : 0;
        __syncthreads();
        part[t] += v;
        __syncthreads();
    }
    int prefix = (t == 0) ? 0 : part[t - 1];
    for (int i = 0; i < chunk; i++) {
        int idx = base + i;
        if (idx < n) {
            offs[idx] = prefix;
            cur[idx] = prefix;
            prefix += deg[idx];
        }
    }
    if (t == 1023) offs[n] = part[1023];
}

__global__ void scatter_kernel(const int* __restrict__ srcArr, const int* __restrict__ dstArr,
                               int* __restrict__ cur, int* __restrict__ csr) {
    int i = blockIdx.x * blockDim.x + threadIdx.x;
    if (i < ETOT) {
        int s, d;
        if (i < NE) {
            s = srcArr[i];
            d = dstArr[i];
        } else {
            s = d = i - NE;
        }
        int pos = atomicAdd(&cur[d], 1);
        csr[pos] = s;
    }
}

// ---------------- layer-1 aggregation: softmax-weighted mean + bias + ELU ---
__global__ void aggregate1(const int* __restrict__ offs, const int* __restrict__ csr,
                           const __bf16* __restrict__ h, const float* __restrict__ alsrc,
                           const float* __restrict__ aldst, const float* __restrict__ bias,
                           __bf16* __restrict__ z) {
    int d = blockIdx.x;
    int c = threadIdx.x;  // 0..255
    int head = c >> 6;
    int e0 = offs[d], e1 = offs[d + 1];
    float ald = aldst[d * HEADS + head];
    float acc = 0.f, wsum = 0.f;
    for (int e = e0; e < e1; ++e) {
        int s = csr[e];
        float x = alsrc[s * HEADS + head] + ald;
        x = (x > 0.f) ? x : SLOPE * x;
        float w = __expf(x);
        wsum += w;
        acc += w * (float)h[(size_t)s * ICH + c];
    }
    float o = acc / (wsum + 1e-16f) + bias[c];
    o = (o > 0.f) ? o : (__expf(o) - 1.f);  // ELU
    z[(size_t)d * ICH + c] = (__bf16)o;
}

// ---------------- layer-2 aggregation: 1 head, 40 ch, + bias --------------
__global__ void aggregate2(const int* __restrict__ offs, const int* __restrict__ csr,
                           const __bf16* __restrict__ h2, const float* __restrict__ alsrc,
                           const float* __restrict__ aldst, const float* __restrict__ bias,
                           float* __restrict__ out, int n) {
    int nl = threadIdx.x >> 6;
    int c = threadIdx.x & 63;
    int d = blockIdx.x * 4 + nl;
    if (d >= n) return;
    bool on = c < OCH;
    int e0 = offs[d], e1 = offs[d + 1];
    float ald = aldst[d];
    float acc = 0.f, wsum = 0.f;
    for (int e = e0; e < e1; ++e) {
        int s = csr[e];
        float x = alsrc[s] + ald;
        x = (x > 0.f) ? x : SLOPE * x;
        float w = __expf(x);
        wsum += w;
        if (on) acc += w * (float)h2[(size_t)s * 128 + c];
    }
    if (on) out[(size_t)d * OCH + c] = acc / (wsum + 1e-16f) + bias[c];
}

extern "C" void kernel_launch(void* const* d_in, const int* in_sizes, int n_in,
                              void* d_out, int out_size, void* d_ws, size_t ws_size,
                              hipStream_t stream) {
    const float* x   = (const float*)d_in[0];
    const int*   ei  = (const int*)d_in[1];
    const float* W1  = (const float*)d_in[2];
    const float* as1 = (const float*)d_in[3];
    const float* ad1 = (const float*)d_in[4];
    const float* b1  = (const float*)d_in[5];
    const float* W2  = (const float*)d_in[6];
    const float* as2 = (const float*)d_in[7];
    const float* ad2 = (const float*)d_in[8];
    const float* b2  = (const float*)d_in[9];
    float* out = (float*)d_out;

    char* ws = (char*)d_ws;
    size_t o = 0;
    auto alloc = [&](size_t bytes) {
        void* p = ws + o;
        o += (bytes + 255) & ~(size_t)255;
        return p;
    };
    __bf16* xb    = (__bf16*)alloc((size_t)MPAD * ICH * 2);
    __bf16* h1    = (__bf16*)alloc((size_t)MPAD * ICH * 2);
    __bf16* z     = (__bf16*)alloc((size_t)MPAD * ICH * 2);
    __bf16* h2    = (__bf16*)alloc((size_t)MPAD * 128 * 2);
    __bf16* W1T   = (__bf16*)alloc((size_t)256 * 256 * 2);
    __bf16* W2T   = (__bf16*)alloc((size_t)128 * 256 * 2);
    float* alsrc1 = (float*)alloc((size_t)NN * HEADS * 4);
    float* aldst1 = (float*)alloc((size_t)NN * HEADS * 4);
    float* alsrc2 = (float*)alloc((size_t)NN * 4);
    float* aldst2 = (float*)alloc((size_t)NN * 4);
    int*   deg    = (int*)alloc((size_t)NN * 4);
    int*   offs   = (int*)alloc((size_t)(NN + 1) * 4);
    int*   cur    = (int*)alloc((size_t)NN * 4);
    int*   csr    = (int*)alloc((size_t)ETOT * 4);

    const int* srcArr = ei;
    const int* dstArr = ei + NE;

    // CSR build (graph shared by both layers)
    hipMemsetAsync(deg, 0, (size_t)NN * 4, stream);
    hist_kernel<<<(ETOT + 255) / 256, 256, 0, stream>>>(dstArr, deg);
    scan_kernel<<<1, 1024, 0, stream>>>(deg, offs, cur, NN);
    scatter_kernel<<<(ETOT + 255) / 256, 256, 0, stream>>>(srcArr, dstArr, cur, csr);

    // bf16 conversions + padding zeroes
    conv_bf16<<<(NN * ICH / 4 + 255) / 256, 256, 0, stream>>>(x, xb, NN * ICH / 4);
    hipMemsetAsync(xb + (size_t)NN * ICH, 0, (size_t)(MPAD - NN) * ICH * 2, stream);
    hipMemsetAsync(z + (size_t)NN * ICH, 0, (size_t)(MPAD - NN) * ICH * 2, stream);
    transW1<<<256, 256, 0, stream>>>(W1, W1T);
    transW2<<<128, 256, 0, stream>>>(W2, W2T);

    // Layer 1
    gemm_mfma<<<dim3(2, MPAD / 128), 256, 0, stream>>>(xb, W1T, h1, 256);
    al_kernel<<<4096, 256, 0, stream>>>(h1, as1, ad1, alsrc1, aldst1, NN, HEADS, HID, ICH);
    aggregate1<<<NN, 256, 0, stream>>>(offs, csr, h1, alsrc1, aldst1, b1, z);

    // Layer 2
    gemm_mfma<<<dim3(1, MPAD / 128), 256, 0, stream>>>(z, W2T, h2, 128);
    al_kernel<<<4096, 64, 0, stream>>>(h2, as2, ad2, alsrc2, aldst2, NN, 1, OCH, 128);
    aggregate2<<<(NN + 3) / 4, 256, 0, stream>>>(offs, csr, h2, alsrc2, aldst2, b2, out, NN);
}

// Round 4
// 476.388 us; speedup vs baseline: 1.9542x; 1.4390x over previous
//
#include <hip/hip_runtime.h>

#define NN 50000
#define MPAD 50048   // 391 * 128
#define ICH 256
#define HID 64
#define HEADS 4
#define OCH 40
#define NE 800000
#define ETOT (NE + NN)
#define SLOPE 0.2f
#define LDP 40  // padded LDS row stride (bf16 elems): 32 data + 8 pad

typedef __bf16 v8bf __attribute__((ext_vector_type(8)));
typedef float v4f __attribute__((ext_vector_type(4)));

// ---------------- fp32 -> bf16 conversion (vectorized) ----------------
__global__ void conv_bf16(const float* __restrict__ in, __bf16* __restrict__ out, int n4) {
    int i = blockIdx.x * blockDim.x + threadIdx.x;
    if (i < n4) {
        float4 v = ((const float4*)in)[i];
        union { __bf16 h[4]; uint2 u; } p;
        p.h[0] = (__bf16)v.x; p.h[1] = (__bf16)v.y;
        p.h[2] = (__bf16)v.z; p.h[3] = (__bf16)v.w;
        ((uint2*)out)[i] = p.u;
    }
}

// W1 [K=256][N=256] fp32 -> W1T [256][256] bf16
__global__ void transW1(const float* __restrict__ W, __bf16* __restrict__ WT) {
    int i = blockIdx.x * blockDim.x + threadIdx.x;  // 65536
    int n = i >> 8, k = i & 255;
    WT[n * 256 + k] = (__bf16)W[k * 256 + n];
}

// W2 [256][40] fp32 -> W2T [128][256] bf16 (zero-padded cols 40..127)
__global__ void transW2(const float* __restrict__ W, __bf16* __restrict__ WT) {
    int i = blockIdx.x * blockDim.x + threadIdx.x;  // 32768
    int n = i >> 8, k = i & 255;
    WT[n * 256 + k] = (n < OCH) ? (__bf16)W[k * OCH + n] : (__bf16)0.f;
}

// ---------------- MFMA GEMM: C[M,128*gx] = A[M,256] @ B^T, bf16 -----------
__global__ __launch_bounds__(256) void gemm_mfma(const __bf16* __restrict__ A,
                                                 const __bf16* __restrict__ B,
                                                 __bf16* __restrict__ C, int ldc) {
    __shared__ __bf16 As[128 * LDP];
    __shared__ __bf16 Bs[128 * LDP];
    int tid = threadIdx.x;
    int lane = tid & 63, wid = tid >> 6;
    int quad = lane >> 4, l15 = lane & 15;
    int wm = (wid & 1) * 64, wn = (wid >> 1) * 64;
    long row0 = (long)blockIdx.y * 128;
    long col0 = (long)blockIdx.x * 128;
    v4f acc[4][4] = {};
    for (int k0 = 0; k0 < 256; k0 += 32) {
#pragma unroll
        for (int i = tid; i < 512; i += 256) {
            int r = i >> 2, q = i & 3;
            *(uint4*)(&As[r * LDP + q * 8]) = *(const uint4*)(A + (row0 + r) * 256 + k0 + q * 8);
            *(uint4*)(&Bs[r * LDP + q * 8]) = *(const uint4*)(B + (col0 + r) * 256 + k0 + q * 8);
        }
        __syncthreads();
        v8bf af[4], bfr[4];
#pragma unroll
        for (int t = 0; t < 4; t++) {
            af[t]  = *(const v8bf*)(&As[(wm + t * 16 + l15) * LDP + quad * 8]);
            bfr[t] = *(const v8bf*)(&Bs[(wn + t * 16 + l15) * LDP + quad * 8]);
        }
#pragma unroll
        for (int mi = 0; mi < 4; mi++)
#pragma unroll
            for (int ni = 0; ni < 4; ni++)
                acc[mi][ni] = __builtin_amdgcn_mfma_f32_16x16x32_bf16(af[mi], bfr[ni], acc[mi][ni], 0, 0, 0);
        __syncthreads();
    }
#pragma unroll
    for (int mi = 0; mi < 4; mi++)
#pragma unroll
        for (int ni = 0; ni < 4; ni++)
#pragma unroll
            for (int r = 0; r < 4; r++) {
                long row = row0 + wm + mi * 16 + quad * 4 + r;
                long col = col0 + wn + ni * 16 + l15;
                C[row * ldc + col] = (__bf16)acc[mi][ni][r];
            }
}

// ------------- layer-1 attention logits: 4 ch/lane, 16-lane xor reduce -----
__global__ void al1_kernel(const __bf16* __restrict__ h, const float* __restrict__ a_s,
                           const float* __restrict__ a_d, float* __restrict__ alsrc,
                           float* __restrict__ aldst) {
    int lane = threadIdx.x & 63, wid = threadIdx.x >> 6;
    int node = blockIdx.x * 4 + wid;
    if (node >= NN) return;
    int head = lane >> 4;
    int c0 = lane * 4;
    float as[4], ad[4];
#pragma unroll
    for (int j = 0; j < 4; j++) { as[j] = a_s[c0 + j]; ad[j] = a_d[c0 + j]; }
    union { uint2 u; __bf16 h4[4]; } p;
    p.u = *(const uint2*)(h + (size_t)node * ICH + c0);
    float vs = 0.f, vd = 0.f;
#pragma unroll
    for (int j = 0; j < 4; j++) {
        float hv = (float)p.h4[j];
        vs += hv * as[j];
        vd += hv * ad[j];
    }
#pragma unroll
    for (int m = 1; m <= 8; m <<= 1) {
        vs += __shfl_xor(vs, m, 64);
        vd += __shfl_xor(vd, m, 64);
    }
    if ((lane & 15) == 0) {
        alsrc[node * HEADS + head] = vs;
        aldst[node * HEADS + head] = vd;
    }
}

// ------------- layer-2 attention logits (1 head, 40 ch) --------------------
__global__ void al2_kernel(const __bf16* __restrict__ h, const float* __restrict__ a_s,
                           const float* __restrict__ a_d, float* __restrict__ alsrc,
                           float* __restrict__ aldst) {
    int lane = threadIdx.x;  // 64
    bool on = lane < OCH;
    float as = on ? a_s[lane] : 0.f;
    float ad = on ? a_d[lane] : 0.f;
    for (int node = blockIdx.x; node < NN; node += gridDim.x) {
        float hv = on ? (float)h[(size_t)node * 128 + lane] : 0.f;
        float vs = hv * as, vd = hv * ad;
#pragma unroll
        for (int off = 32; off > 0; off >>= 1) {
            vs += __shfl_down(vs, off, 64);
            vd += __shfl_down(vd, off, 64);
        }
        if (lane == 0) {
            alsrc[node] = vs;
            aldst[node] = vd;
        }
    }
}

// ---------------- CSR build ----------------
__global__ void hist_kernel(const int* __restrict__ dstArr, int* __restrict__ deg) {
    int i = blockIdx.x * blockDim.x + threadIdx.x;
    if (i < ETOT) {
        int d = (i < NE) ? dstArr[i] : (i - NE);
        atomicAdd(&deg[d], 1);
    }
}

__global__ void scan_kernel(const int* __restrict__ deg, int* __restrict__ offs,
                            int* __restrict__ cur, int n) {
    __shared__ int part[1024];
    int t = threadIdx.x;
    int chunk = (n + 1023) / 1024;
    int base = t * chunk;
    int s = 0;
    for (int i = 0; i < chunk; i++) {
        int idx = base + i;
        if (idx < n) s += deg[idx];
    }
    part[t] = s;
    __syncthreads();
    for (int d = 1; d < 1024; d <<= 1) {
        int v = (t >= d) ? part[t - d] : 0;
        __syncthreads();
        part[t] += v;
        __syncthreads();
    }
    int prefix = (t == 0) ? 0 : part[t - 1];
    for (int i = 0; i < chunk; i++) {
        int idx = base + i;
        if (idx < n) {
            offs[idx] = prefix;
            cur[idx] = prefix;
            prefix += deg[idx];
        }
    }
    if (t == 1023) offs[n] = part[1023];
}

__global__ void scatter_kernel(const int* __restrict__ srcArr, const int* __restrict__ dstArr,
                               int* __restrict__ cur, int* __restrict__ csr) {
    int i = blockIdx.x * blockDim.x + threadIdx.x;
    if (i < ETOT) {
        int s, d;
        if (i < NE) {
            s = srcArr[i];
            d = dstArr[i];
        } else {
            s = d = i - NE;
        }
        int pos = atomicAdd(&cur[d], 1);
        csr[pos] = s;
    }
}

// -------- layer-1 aggregation: one wave per dst; 2 edge-slots x 32 cg ------
__global__ __launch_bounds__(256) void aggregate1(
        const int* __restrict__ offs, const int* __restrict__ csr,
        const __bf16* __restrict__ h, const float* __restrict__ alsrc,
        const float* __restrict__ aldst, const float* __restrict__ bias,
        __bf16* __restrict__ z) {
    int lane = threadIdx.x & 63, wid = threadIdx.x >> 6;
    int d = blockIdx.x * 4 + wid;
    if (d >= NN) return;
    int es = lane >> 5;        // edge slot 0..1
    int cg = lane & 31;        // channel group: 8 ch each
    int head = cg >> 3;
    int e0 = offs[d], e1 = offs[d + 1];
    float ald = aldst[d * HEADS + head];
    float acc[8] = {};
    float wsum = 0.f;
    for (int e = e0 + es; e < e1; e += 2) {
        int s = csr[e];
        float x = alsrc[s * HEADS + head] + ald;
        x = (x > 0.f) ? x : SLOPE * x;
        float w = __expf(x);
        wsum += w;
        v8bf hv = *(const v8bf*)(h + (size_t)s * ICH + cg * 8);
#pragma unroll
        for (int j = 0; j < 8; j++) acc[j] += w * (float)hv[j];
    }
    // merge the two edge slots (lane <-> lane+32)
#pragma unroll
    for (int j = 0; j < 8; j++) acc[j] += __shfl_down(acc[j], 32, 64);
    wsum += __shfl_down(wsum, 32, 64);
    if (es == 0) {
        float inv = 1.f / (wsum + 1e-16f);
        union { __bf16 hh[8]; uint4 u; } p;
#pragma unroll
        for (int j = 0; j < 8; j++) {
            float o = acc[j] * inv + bias[cg * 8 + j];
            o = (o > 0.f) ? o : (__expf(o) - 1.f);  // ELU
            p.hh[j] = (__bf16)o;
        }
        *(uint4*)(z + (size_t)d * ICH + cg * 8) = p.u;
    }
}

// -------- layer-2 aggregation: one wave per dst; 8 edge-slots x 8 cg -------
__global__ __launch_bounds__(256) void aggregate2(
        const int* __restrict__ offs, const int* __restrict__ csr,
        const __bf16* __restrict__ h2, const float* __restrict__ alsrc,
        const float* __restrict__ aldst, const float* __restrict__ bias,
        float* __restrict__ out) {
    int lane = threadIdx.x & 63, wid = threadIdx.x >> 6;
    int d = blockIdx.x * 4 + wid;
    if (d >= NN) return;
    int es = lane >> 3;        // edge slot 0..7
    int cg = lane & 7;         // channel group: 8 ch each; cg<5 valid (40 ch)
    bool on = cg < 5;
    int e0 = offs[d], e1 = offs[d + 1];
    float ald = aldst[d];
    float acc[8] = {};
    float wsum = 0.f;
    for (int e = e0 + es; e < e1; e += 8) {
        int s = csr[e];
        float x = alsrc[s] + ald;
        x = (x > 0.f) ? x : SLOPE * x;
        float w = __expf(x);
        wsum += w;
        if (on) {
            v8bf hv = *(const v8bf*)(h2 + (size_t)s * 128 + cg * 8);
#pragma unroll
            for (int j = 0; j < 8; j++) acc[j] += w * (float)hv[j];
        }
    }
#pragma unroll
    for (int m = 8; m <= 32; m <<= 1) {
#pragma unroll
        for (int j = 0; j < 8; j++) acc[j] += __shfl_xor(acc[j], m, 64);
        wsum += __shfl_xor(wsum, m, 64);
    }
    if (es == 0 && on) {
        float inv = 1.f / (wsum + 1e-16f);
#pragma unroll
        for (int j = 0; j < 8; j++)
            out[(size_t)d * OCH + cg * 8 + j] = acc[j] * inv + bias[cg * 8 + j];
    }
}

extern "C" void kernel_launch(void* const* d_in, const int* in_sizes, int n_in,
                              void* d_out, int out_size, void* d_ws, size_t ws_size,
                              hipStream_t stream) {
    const float* x   = (const float*)d_in[0];
    const int*   ei  = (const int*)d_in[1];
    const float* W1  = (const float*)d_in[2];
    const float* as1 = (const float*)d_in[3];
    const float* ad1 = (const float*)d_in[4];
    const float* b1  = (const float*)d_in[5];
    const float* W2  = (const float*)d_in[6];
    const float* as2 = (const float*)d_in[7];
    const float* ad2 = (const float*)d_in[8];
    const float* b2  = (const float*)d_in[9];
    float* out = (float*)d_out;

    char* ws = (char*)d_ws;
    size_t o = 0;
    auto alloc = [&](size_t bytes) {
        void* p = ws + o;
        o += (bytes + 255) & ~(size_t)255;
        return p;
    };
    __bf16* xb    = (__bf16*)alloc((size_t)MPAD * ICH * 2);
    __bf16* h1    = (__bf16*)alloc((size_t)MPAD * ICH * 2);
    __bf16* z     = (__bf16*)alloc((size_t)MPAD * ICH * 2);
    __bf16* h2    = (__bf16*)alloc((size_t)MPAD * 128 * 2);
    __bf16* W1T   = (__bf16*)alloc((size_t)256 * 256 * 2);
    __bf16* W2T   = (__bf16*)alloc((size_t)128 * 256 * 2);
    float* alsrc1 = (float*)alloc((size_t)NN * HEADS * 4);
    float* aldst1 = (float*)alloc((size_t)NN * HEADS * 4);
    float* alsrc2 = (float*)alloc((size_t)NN * 4);
    float* aldst2 = (float*)alloc((size_t)NN * 4);
    int*   deg    = (int*)alloc((size_t)NN * 4);
    int*   offs   = (int*)alloc((size_t)(NN + 1) * 4);
    int*   cur    = (int*)alloc((size_t)NN * 4);
    int*   csr    = (int*)alloc((size_t)ETOT * 4);

    const int* srcArr = ei;
    const int* dstArr = ei + NE;

    // CSR build (graph shared by both layers)
    hipMemsetAsync(deg, 0, (size_t)NN * 4, stream);
    hist_kernel<<<(ETOT + 255) / 256, 256, 0, stream>>>(dstArr, deg);
    scan_kernel<<<1, 1024, 0, stream>>>(deg, offs, cur, NN);
    scatter_kernel<<<(ETOT + 255) / 256, 256, 0, stream>>>(srcArr, dstArr, cur, csr);

    // bf16 conversions + padding zeroes
    conv_bf16<<<(NN * ICH / 4 + 255) / 256, 256, 0, stream>>>(x, xb, NN * ICH / 4);
    hipMemsetAsync(xb + (size_t)NN * ICH, 0, (size_t)(MPAD - NN) * ICH * 2, stream);
    hipMemsetAsync(z + (size_t)NN * ICH, 0, (size_t)(MPAD - NN) * ICH * 2, stream);
    transW1<<<256, 256, 0, stream>>>(W1, W1T);
    transW2<<<128, 256, 0, stream>>>(W2, W2T);

    // Layer 1
    gemm_mfma<<<dim3(2, MPAD / 128), 256, 0, stream>>>(xb, W1T, h1, 256);
    al1_kernel<<<(NN + 3) / 4, 256, 0, stream>>>(h1, as1, ad1, alsrc1, aldst1);
    aggregate1<<<(NN + 3) / 4, 256, 0, stream>>>(offs, csr, h1, alsrc1, aldst1, b1, z);

    // Layer 2
    gemm_mfma<<<dim3(1, MPAD / 128), 256, 0, stream>>>(z, W2T, h2, 128);
    al2_kernel<<<4096, 64, 0, stream>>>(h2, as2, ad2, alsrc2, aldst2);
    aggregate2<<<(NN + 3) / 4, 256, 0, stream>>>(offs, csr, h2, alsrc2, aldst2, b2, out);
}

// Round 5
// 357.877 us; speedup vs baseline: 2.6013x; 1.3311x over previous
//
#include <hip/hip_runtime.h>

#define NN 50000
#define MPAD 50048   // 391 * 128
#define ICH 256
#define HID 64
#define HEADS 4
#define OCH 40
#define NE 800000
#define ETOT (NE + NN)
#define SLOPE 0.2f
#define LDP 40       // padded LDS row stride (bf16 elems): 32 data + 8 pad
#define SCAN_B 196   // 196 * 256 = 50176 >= NN

typedef __bf16 v8bf __attribute__((ext_vector_type(8)));
typedef float v4f __attribute__((ext_vector_type(4)));

// ---------------- fp32 -> bf16 conversion (vectorized) ----------------
__global__ void conv_bf16(const float* __restrict__ in, __bf16* __restrict__ out, int n4) {
    int i = blockIdx.x * blockDim.x + threadIdx.x;
    if (i < n4) {
        float4 v = ((const float4*)in)[i];
        union { __bf16 h[4]; uint2 u; } p;
        p.h[0] = (__bf16)v.x; p.h[1] = (__bf16)v.y;
        p.h[2] = (__bf16)v.z; p.h[3] = (__bf16)v.w;
        ((uint2*)out)[i] = p.u;
    }
}

// W1 [K=256][N=256] fp32 -> W1T [256][256] bf16
__global__ void transW1(const float* __restrict__ W, __bf16* __restrict__ WT) {
    int i = blockIdx.x * blockDim.x + threadIdx.x;  // 65536
    int n = i >> 8, k = i & 255;
    WT[n * 256 + k] = (__bf16)W[k * 256 + n];
}

// W2 [256][40] fp32 -> W2T [128][256] bf16 (zero-padded cols 40..127)
__global__ void transW2(const float* __restrict__ W, __bf16* __restrict__ WT) {
    int i = blockIdx.x * blockDim.x + threadIdx.x;  // 32768
    int n = i >> 8, k = i & 255;
    WT[n * 256 + k] = (n < OCH) ? (__bf16)W[k * OCH + n] : (__bf16)0.f;
}

// ---------------- MFMA GEMM: C[M,128*gx] = A[M,256] @ B^T, bf16 -----------
__global__ __launch_bounds__(256) void gemm_mfma(const __bf16* __restrict__ A,
                                                 const __bf16* __restrict__ B,
                                                 __bf16* __restrict__ C, int ldc) {
    __shared__ __bf16 As[128 * LDP];
    __shared__ __bf16 Bs[128 * LDP];
    int tid = threadIdx.x;
    int lane = tid & 63, wid = tid >> 6;
    int quad = lane >> 4, l15 = lane & 15;
    int wm = (wid & 1) * 64, wn = (wid >> 1) * 64;
    long row0 = (long)blockIdx.y * 128;
    long col0 = (long)blockIdx.x * 128;
    v4f acc[4][4] = {};
    for (int k0 = 0; k0 < 256; k0 += 32) {
#pragma unroll
        for (int i = tid; i < 512; i += 256) {
            int r = i >> 2, q = i & 3;
            *(uint4*)(&As[r * LDP + q * 8]) = *(const uint4*)(A + (row0 + r) * 256 + k0 + q * 8);
            *(uint4*)(&Bs[r * LDP + q * 8]) = *(const uint4*)(B + (col0 + r) * 256 + k0 + q * 8);
        }
        __syncthreads();
        v8bf af[4], bfr[4];
#pragma unroll
        for (int t = 0; t < 4; t++) {
            af[t]  = *(const v8bf*)(&As[(wm + t * 16 + l15) * LDP + quad * 8]);
            bfr[t] = *(const v8bf*)(&Bs[(wn + t * 16 + l15) * LDP + quad * 8]);
        }
#pragma unroll
        for (int mi = 0; mi < 4; mi++)
#pragma unroll
            for (int ni = 0; ni < 4; ni++)
                acc[mi][ni] = __builtin_amdgcn_mfma_f32_16x16x32_bf16(af[mi], bfr[ni], acc[mi][ni], 0, 0, 0);
        __syncthreads();
    }
#pragma unroll
    for (int mi = 0; mi < 4; mi++)
#pragma unroll
        for (int ni = 0; ni < 4; ni++)
#pragma unroll
            for (int r = 0; r < 4; r++) {
                long row = row0 + wm + mi * 16 + quad * 4 + r;
                long col = col0 + wn + ni * 16 + l15;
                C[row * ldc + col] = (__bf16)acc[mi][ni][r];
            }
}

// ------------- layer-1 attention logits: 4 ch/lane, 16-lane xor reduce -----
__global__ void al1_kernel(const __bf16* __restrict__ h, const float* __restrict__ a_s,
                           const float* __restrict__ a_d, float* __restrict__ alsrc,
                           float* __restrict__ aldst) {
    int lane = threadIdx.x & 63, wid = threadIdx.x >> 6;
    int node = blockIdx.x * 4 + wid;
    if (node >= NN) return;
    int head = lane >> 4;
    int c0 = lane * 4;
    float as[4], ad[4];
#pragma unroll
    for (int j = 0; j < 4; j++) { as[j] = a_s[c0 + j]; ad[j] = a_d[c0 + j]; }
    union { uint2 u; __bf16 h4[4]; } p;
    p.u = *(const uint2*)(h + (size_t)node * ICH + c0);
    float vs = 0.f, vd = 0.f;
#pragma unroll
    for (int j = 0; j < 4; j++) {
        float hv = (float)p.h4[j];
        vs += hv * as[j];
        vd += hv * ad[j];
    }
#pragma unroll
    for (int m = 1; m <= 8; m <<= 1) {
        vs += __shfl_xor(vs, m, 64);
        vd += __shfl_xor(vd, m, 64);
    }
    if ((lane & 15) == 0) {
        alsrc[node * HEADS + head] = vs;
        aldst[node * HEADS + head] = vd;
    }
}

// ------------- layer-2 attention logits (1 head, 40 ch) --------------------
__global__ void al2_kernel(const __bf16* __restrict__ h, const float* __restrict__ a_s,
                           const float* __restrict__ a_d, float* __restrict__ alsrc,
                           float* __restrict__ aldst) {
    int lane = threadIdx.x;  // 64
    bool on = lane < OCH;
    float as = on ? a_s[lane] : 0.f;
    float ad = on ? a_d[lane] : 0.f;
    for (int node = blockIdx.x; node < NN; node += gridDim.x) {
        float hv = on ? (float)h[(size_t)node * 128 + lane] : 0.f;
        float vs = hv * as, vd = hv * ad;
#pragma unroll
        for (int off = 32; off > 0; off >>= 1) {
            vs += __shfl_down(vs, off, 64);
            vd += __shfl_down(vd, off, 64);
        }
        if (lane == 0) {
            alsrc[node] = vs;
            aldst[node] = vd;
        }
    }
}

// ---------------- CSR build ----------------
__global__ void hist_kernel(const int* __restrict__ dstArr, int* __restrict__ deg) {
    int i = blockIdx.x * blockDim.x + threadIdx.x;
    if (i < ETOT) {
        int d = (i < NE) ? dstArr[i] : (i - NE);
        atomicAdd(&deg[d], 1);
    }
}

// block-level exclusive scan helper (256 threads, 4 waves)
__device__ __forceinline__ int block_excl_scan(int v, int tid, int* wsum) {
    int lane = tid & 63, w = tid >> 6;
    int x = v;
#pragma unroll
    for (int off = 1; off < 64; off <<= 1) {
        int t = __shfl_up(x, off, 64);
        if (lane >= off) x += t;
    }
    if (lane == 63) wsum[w] = x;
    __syncthreads();
    int base = 0;
    for (int i = 0; i < w; i++) base += wsum[i];
    return base + x - v;
}

// 1) per-block sums of deg
__global__ __launch_bounds__(256) void blocksum_kernel(const int* __restrict__ deg,
                                                       int* __restrict__ bsum) {
    __shared__ int wsum[4];
    int i = blockIdx.x * 256 + threadIdx.x;
    int v = (i < NN) ? deg[i] : 0;
#pragma unroll
    for (int m = 1; m <= 32; m <<= 1) v += __shfl_xor(v, m, 64);
    if ((threadIdx.x & 63) == 0) wsum[threadIdx.x >> 6] = v;
    __syncthreads();
    if (threadIdx.x == 0) bsum[blockIdx.x] = wsum[0] + wsum[1] + wsum[2] + wsum[3];
}

// 2) exclusive scan of the SCAN_B block sums (single small block)
__global__ __launch_bounds__(256) void scan_bsum(const int* __restrict__ bsum,
                                                 int* __restrict__ bexcl) {
    __shared__ int wsum[4];
    int t = threadIdx.x;
    int v = (t < SCAN_B) ? bsum[t] : 0;
    int excl = block_excl_scan(v, t, wsum);
    if (t < SCAN_B) bexcl[t] = excl;
}

// 3) final: per-element exclusive prefix + block base -> offs, cur
__global__ __launch_bounds__(256) void scan_final(const int* __restrict__ deg,
                                                  const int* __restrict__ bexcl,
                                                  int* __restrict__ offs,
                                                  int* __restrict__ cur) {
    __shared__ int wsum[4];
    int i = blockIdx.x * 256 + threadIdx.x;
    int v = (i < NN) ? deg[i] : 0;
    int excl = block_excl_scan(v, threadIdx.x, wsum) + bexcl[blockIdx.x];
    if (i < NN) {
        offs[i] = excl;
        cur[i] = excl;
        if (i == NN - 1) offs[NN] = excl + v;
    }
}

__global__ void scatter_kernel(const int* __restrict__ srcArr, const int* __restrict__ dstArr,
                               int* __restrict__ cur, int* __restrict__ csr) {
    int i = blockIdx.x * blockDim.x + threadIdx.x;
    if (i < ETOT) {
        int s, d;
        if (i < NE) {
            s = srcArr[i];
            d = dstArr[i];
        } else {
            s = d = i - NE;
        }
        int pos = atomicAdd(&cur[d], 1);
        csr[pos] = s;
    }
}

// -------- layer-1 aggregation: one wave per dst; 2 edge-slots x 32 cg ------
__global__ __launch_bounds__(256) void aggregate1(
        const int* __restrict__ offs, const int* __restrict__ csr,
        const __bf16* __restrict__ h, const float* __restrict__ alsrc,
        const float* __restrict__ aldst, const float* __restrict__ bias,
        __bf16* __restrict__ z) {
    int lane = threadIdx.x & 63, wid = threadIdx.x >> 6;
    int d = blockIdx.x * 4 + wid;
    if (d >= NN) return;
    int es = lane >> 5;        // edge slot 0..1
    int cg = lane & 31;        // channel group: 8 ch each
    int head = cg >> 3;
    int e0 = offs[d], e1 = offs[d + 1];
    float ald = aldst[d * HEADS + head];
    float acc[8] = {};
    float wsum = 0.f;
    for (int e = e0 + es; e < e1; e += 2) {
        int s = csr[e];
        float x = alsrc[s * HEADS + head] + ald;
        x = (x > 0.f) ? x : SLOPE * x;
        float w = __expf(x);
        wsum += w;
        v8bf hv = *(const v8bf*)(h + (size_t)s * ICH + cg * 8);
#pragma unroll
        for (int j = 0; j < 8; j++) acc[j] += w * (float)hv[j];
    }
#pragma unroll
    for (int j = 0; j < 8; j++) acc[j] += __shfl_down(acc[j], 32, 64);
    wsum += __shfl_down(wsum, 32, 64);
    if (es == 0) {
        float inv = 1.f / (wsum + 1e-16f);
        union { __bf16 hh[8]; uint4 u; } p;
#pragma unroll
        for (int j = 0; j < 8; j++) {
            float o = acc[j] * inv + bias[cg * 8 + j];
            o = (o > 0.f) ? o : (__expf(o) - 1.f);  // ELU
            p.hh[j] = (__bf16)o;
        }
        *(uint4*)(z + (size_t)d * ICH + cg * 8) = p.u;
    }
}

// -------- layer-2 aggregation: one wave per dst; 8 edge-slots x 8 cg -------
__global__ __launch_bounds__(256) void aggregate2(
        const int* __restrict__ offs, const int* __restrict__ csr,
        const __bf16* __restrict__ h2, const float* __restrict__ alsrc,
        const float* __restrict__ aldst, const float* __restrict__ bias,
        float* __restrict__ out) {
    int lane = threadIdx.x & 63, wid = threadIdx.x >> 6;
    int d = blockIdx.x * 4 + wid;
    if (d >= NN) return;
    int es = lane >> 3;        // edge slot 0..7
    int cg = lane & 7;         // channel group: 8 ch each; cg<5 valid (40 ch)
    bool on = cg < 5;
    int e0 = offs[d], e1 = offs[d + 1];
    float ald = aldst[d];
    float acc[8] = {};
    float wsum = 0.f;
    for (int e = e0 + es; e < e1; e += 8) {
        int s = csr[e];
        float x = alsrc[s] + ald;
        x = (x > 0.f) ? x : SLOPE * x;
        float w = __expf(x);
        wsum += w;
        if (on) {
            v8bf hv = *(const v8bf*)(h2 + (size_t)s * 128 + cg * 8);
#pragma unroll
            for (int j = 0; j < 8; j++) acc[j] += w * (float)hv[j];
        }
    }
#pragma unroll
    for (int m = 8; m <= 32; m <<= 1) {
#pragma unroll
        for (int j = 0; j < 8; j++) acc[j] += __shfl_xor(acc[j], m, 64);
        wsum += __shfl_xor(wsum, m, 64);
    }
    if (es == 0 && on) {
        float inv = 1.f / (wsum + 1e-16f);
#pragma unroll
        for (int j = 0; j < 8; j++)
            out[(size_t)d * OCH + cg * 8 + j] = acc[j] * inv + bias[cg * 8 + j];
    }
}

extern "C" void kernel_launch(void* const* d_in, const int* in_sizes, int n_in,
                              void* d_out, int out_size, void* d_ws, size_t ws_size,
                              hipStream_t stream) {
    const float* x   = (const float*)d_in[0];
    const int*   ei  = (const int*)d_in[1];
    const float* W1  = (const float*)d_in[2];
    const float* as1 = (const float*)d_in[3];
    const float* ad1 = (const float*)d_in[4];
    const float* b1  = (const float*)d_in[5];
    const float* W2  = (const float*)d_in[6];
    const float* as2 = (const float*)d_in[7];
    const float* ad2 = (const float*)d_in[8];
    const float* b2  = (const float*)d_in[9];
    float* out = (float*)d_out;

    char* ws = (char*)d_ws;
    size_t o = 0;
    auto alloc = [&](size_t bytes) {
        void* p = ws + o;
        o += (bytes + 255) & ~(size_t)255;
        return p;
    };
    __bf16* xb    = (__bf16*)alloc((size_t)MPAD * ICH * 2);
    __bf16* h1    = (__bf16*)alloc((size_t)MPAD * ICH * 2);
    __bf16* z     = (__bf16*)alloc((size_t)MPAD * ICH * 2);
    __bf16* h2    = (__bf16*)alloc((size_t)MPAD * 128 * 2);
    __bf16* W1T   = (__bf16*)alloc((size_t)256 * 256 * 2);
    __bf16* W2T   = (__bf16*)alloc((size_t)128 * 256 * 2);
    float* alsrc1 = (float*)alloc((size_t)NN * HEADS * 4);
    float* aldst1 = (float*)alloc((size_t)NN * HEADS * 4);
    float* alsrc2 = (float*)alloc((size_t)NN * 4);
    float* aldst2 = (float*)alloc((size_t)NN * 4);
    int*   deg    = (int*)alloc((size_t)NN * 4);
    int*   offs   = (int*)alloc((size_t)(NN + 1) * 4);
    int*   cur    = (int*)alloc((size_t)NN * 4);
    int*   csr    = (int*)alloc((size_t)ETOT * 4);
    int*   bsum   = (int*)alloc((size_t)SCAN_B * 4);
    int*   bexcl  = (int*)alloc((size_t)SCAN_B * 4);

    const int* srcArr = ei;
    const int* dstArr = ei + NE;

    // CSR build (graph shared by both layers)
    hipMemsetAsync(deg, 0, (size_t)NN * 4, stream);
    hist_kernel<<<(ETOT + 255) / 256, 256, 0, stream>>>(dstArr, deg);
    blocksum_kernel<<<SCAN_B, 256, 0, stream>>>(deg, bsum);
    scan_bsum<<<1, 256, 0, stream>>>(bsum, bexcl);
    scan_final<<<SCAN_B, 256, 0, stream>>>(deg, bexcl, offs, cur);
    scatter_kernel<<<(ETOT + 255) / 256, 256, 0, stream>>>(srcArr, dstArr, cur, csr);

    // bf16 conversions + padding zeroes
    conv_bf16<<<(NN * ICH / 4 + 255) / 256, 256, 0, stream>>>(x, xb, NN * ICH / 4);
    hipMemsetAsync(xb + (size_t)NN * ICH, 0, (size_t)(MPAD - NN) * ICH * 2, stream);
    hipMemsetAsync(z + (size_t)NN * ICH, 0, (size_t)(MPAD - NN) * ICH * 2, stream);
    transW1<<<256, 256, 0, stream>>>(W1, W1T);
    transW2<<<128, 256, 0, stream>>>(W2, W2T);

    // Layer 1
    gemm_mfma<<<dim3(2, MPAD / 128), 256, 0, stream>>>(xb, W1T, h1, 256);
    al1_kernel<<<(NN + 3) / 4, 256, 0, stream>>>(h1, as1, ad1, alsrc1, aldst1);
    aggregate1<<<(NN + 3) / 4, 256, 0, stream>>>(offs, csr, h1, alsrc1, aldst1, b1, z);

    // Layer 2
    gemm_mfma<<<dim3(1, MPAD / 128), 256, 0, stream>>>(z, W2T, h2, 128);
    al2_kernel<<<4096, 64, 0, stream>>>(h2, as2, ad2, alsrc2, aldst2);
    aggregate2<<<(NN + 3) / 4, 256, 0, stream>>>(offs, csr, h2, alsrc2, aldst2, b2, out);
}

// Round 6
// 348.403 us; speedup vs baseline: 2.6720x; 1.0272x over previous
//
#include <hip/hip_runtime.h>

#define NN 50000
#define MPAD 50048   // 391 * 128
#define ICH 256
#define HID 64
#define HEADS 4
#define OCH 40
#define NE 800000
#define ETOT (NE + NN)
#define SLOPE 0.2f
#define LDP 40       // padded LDS row stride (bf16 elems): 32 data + 8 pad
#define SCAN_B 196   // 196 * 256 = 50176 >= NN

typedef __bf16 v8bf __attribute__((ext_vector_type(8)));
typedef float v4f __attribute__((ext_vector_type(4)));

// ------- fp32 -> bf16 conversion, with zero-fill of padding rows ----------
__global__ void conv_pad(const float* __restrict__ in, __bf16* __restrict__ out) {
    int i = blockIdx.x * blockDim.x + threadIdx.x;  // groups of 4 elems
    if (i < NN * ICH / 4) {
        float4 v = ((const float4*)in)[i];
        union { __bf16 h[4]; uint2 u; } p;
        p.h[0] = (__bf16)v.x; p.h[1] = (__bf16)v.y;
        p.h[2] = (__bf16)v.z; p.h[3] = (__bf16)v.w;
        ((uint2*)out)[i] = p.u;
    } else if (i < MPAD * ICH / 4) {
        ((uint2*)out)[i] = uint2{0u, 0u};
    }
}

// W1 [256][256] -> W1T [256][256] bf16 ; W2 [256][40] -> W2T [128][256] bf16
__global__ void transW(const float* __restrict__ W1, const float* __restrict__ W2,
                       __bf16* __restrict__ W1T, __bf16* __restrict__ W2T) {
    int i = blockIdx.x * blockDim.x + threadIdx.x;
    if (i < 65536) {
        int n = i >> 8, k = i & 255;
        W1T[n * 256 + k] = (__bf16)W1[k * 256 + n];
    } else {
        int j = i - 65536;  // 0..32767
        int n = j >> 8, k = j & 255;
        W2T[n * 256 + k] = (n < OCH) ? (__bf16)W2[k * OCH + n] : (__bf16)0.f;
    }
}

// ---------------- MFMA GEMM: C[M, ncol] = A[M,256] @ B^T, bf16 ------------
__global__ __launch_bounds__(256) void gemm_mfma(const __bf16* __restrict__ A,
                                                 const __bf16* __restrict__ B,
                                                 __bf16* __restrict__ C, int ldc, int ncol) {
    __shared__ __bf16 As[128 * LDP];
    __shared__ __bf16 Bs[128 * LDP];
    int tid = threadIdx.x;
    int lane = tid & 63, wid = tid >> 6;
    int quad = lane >> 4, l15 = lane & 15;
    int wm = (wid & 1) * 64, wn = (wid >> 1) * 64;
    long row0 = (long)blockIdx.y * 128;
    long col0 = (long)blockIdx.x * 128;
    v4f acc[4][4] = {};
    for (int k0 = 0; k0 < 256; k0 += 32) {
#pragma unroll
        for (int i = tid; i < 512; i += 256) {
            int r = i >> 2, q = i & 3;
            *(uint4*)(&As[r * LDP + q * 8]) = *(const uint4*)(A + (row0 + r) * 256 + k0 + q * 8);
            *(uint4*)(&Bs[r * LDP + q * 8]) = *(const uint4*)(B + (col0 + r) * 256 + k0 + q * 8);
        }
        __syncthreads();
        v8bf af[4], bfr[4];
#pragma unroll
        for (int t = 0; t < 4; t++) {
            af[t]  = *(const v8bf*)(&As[(wm + t * 16 + l15) * LDP + quad * 8]);
            bfr[t] = *(const v8bf*)(&Bs[(wn + t * 16 + l15) * LDP + quad * 8]);
        }
#pragma unroll
        for (int mi = 0; mi < 4; mi++)
#pragma unroll
            for (int ni = 0; ni < 4; ni++)
                acc[mi][ni] = __builtin_amdgcn_mfma_f32_16x16x32_bf16(af[mi], bfr[ni], acc[mi][ni], 0, 0, 0);
        __syncthreads();
    }
#pragma unroll
    for (int mi = 0; mi < 4; mi++)
#pragma unroll
        for (int ni = 0; ni < 4; ni++)
#pragma unroll
            for (int r = 0; r < 4; r++) {
                long row = row0 + wm + mi * 16 + quad * 4 + r;
                long col = col0 + wn + ni * 16 + l15;
                if (col < ncol) C[row * ldc + col] = (__bf16)acc[mi][ni][r];
            }
}

// ------------- layer-1 attention logits: 4 ch/lane, 16-lane xor reduce -----
__global__ void al1_kernel(const __bf16* __restrict__ h, const float* __restrict__ a_s,
                           const float* __restrict__ a_d, float* __restrict__ alsrc,
                           float* __restrict__ aldst) {
    int lane = threadIdx.x & 63, wid = threadIdx.x >> 6;
    int node = blockIdx.x * 4 + wid;
    if (node >= NN) return;
    int head = lane >> 4;
    int c0 = lane * 4;
    float as[4], ad[4];
#pragma unroll
    for (int j = 0; j < 4; j++) { as[j] = a_s[c0 + j]; ad[j] = a_d[c0 + j]; }
    union { uint2 u; __bf16 h4[4]; } p;
    p.u = *(const uint2*)(h + (size_t)node * ICH + c0);
    float vs = 0.f, vd = 0.f;
#pragma unroll
    for (int j = 0; j < 4; j++) {
        float hv = (float)p.h4[j];
        vs += hv * as[j];
        vd += hv * ad[j];
    }
#pragma unroll
    for (int m = 1; m <= 8; m <<= 1) {
        vs += __shfl_xor(vs, m, 64);
        vd += __shfl_xor(vd, m, 64);
    }
    if ((lane & 15) == 0) {
        alsrc[node * HEADS + head] = vs;
        aldst[node * HEADS + head] = vd;
    }
}

// ------------- layer-2 attention logits (1 head, 40 ch, compact h2) -------
__global__ void al2_kernel(const __bf16* __restrict__ h, const float* __restrict__ a_s,
                           const float* __restrict__ a_d, float* __restrict__ alsrc,
                           float* __restrict__ aldst) {
    int lane = threadIdx.x;  // 64
    bool on = lane < OCH;
    float as = on ? a_s[lane] : 0.f;
    float ad = on ? a_d[lane] : 0.f;
    for (int node = blockIdx.x; node < NN; node += gridDim.x) {
        float hv = on ? (float)h[(size_t)node * OCH + lane] : 0.f;
        float vs = hv * as, vd = hv * ad;
#pragma unroll
        for (int off = 32; off > 0; off >>= 1) {
            vs += __shfl_down(vs, off, 64);
            vd += __shfl_down(vd, off, 64);
        }
        if (lane == 0) {
            alsrc[node] = vs;
            aldst[node] = vd;
        }
    }
}

// ---------------- CSR build ----------------
__global__ void hist_kernel(const int* __restrict__ dstArr, int* __restrict__ deg) {
    int i = blockIdx.x * blockDim.x + threadIdx.x;
    if (i < ETOT) {
        int d = (i < NE) ? dstArr[i] : (i - NE);
        atomicAdd(&deg[d], 1);
    }
}

__device__ __forceinline__ int block_excl_scan(int v, int tid, int* wsum) {
    int lane = tid & 63, w = tid >> 6;
    int x = v;
#pragma unroll
    for (int off = 1; off < 64; off <<= 1) {
        int t = __shfl_up(x, off, 64);
        if (lane >= off) x += t;
    }
    if (lane == 63) wsum[w] = x;
    __syncthreads();
    int base = 0;
    for (int i = 0; i < w; i++) base += wsum[i];
    return base + x - v;
}

__global__ __launch_bounds__(256) void blocksum_kernel(const int* __restrict__ deg,
                                                       int* __restrict__ bsum) {
    __shared__ int wsum[4];
    int i = blockIdx.x * 256 + threadIdx.x;
    int v = (i < NN) ? deg[i] : 0;
#pragma unroll
    for (int m = 1; m <= 32; m <<= 1) v += __shfl_xor(v, m, 64);
    if ((threadIdx.x & 63) == 0) wsum[threadIdx.x >> 6] = v;
    __syncthreads();
    if (threadIdx.x == 0) bsum[blockIdx.x] = wsum[0] + wsum[1] + wsum[2] + wsum[3];
}

__global__ __launch_bounds__(256) void scan_bsum(const int* __restrict__ bsum,
                                                 int* __restrict__ bexcl) {
    __shared__ int wsum[4];
    int t = threadIdx.x;
    int v = (t < SCAN_B) ? bsum[t] : 0;
    int excl = block_excl_scan(v, t, wsum);
    if (t < SCAN_B) bexcl[t] = excl;
}

__global__ __launch_bounds__(256) void scan_final(const int* __restrict__ deg,
                                                  const int* __restrict__ bexcl,
                                                  int* __restrict__ offs,
                                                  int* __restrict__ cur) {
    __shared__ int wsum[4];
    int i = blockIdx.x * 256 + threadIdx.x;
    int v = (i < NN) ? deg[i] : 0;
    int excl = block_excl_scan(v, threadIdx.x, wsum) + bexcl[blockIdx.x];
    if (i < NN) {
        offs[i] = excl;
        cur[i] = excl;
        if (i == NN - 1) offs[NN] = excl + v;
    }
}

__global__ void scatter_kernel(const int* __restrict__ srcArr, const int* __restrict__ dstArr,
                               int* __restrict__ cur, int* __restrict__ csr) {
    int i = blockIdx.x * blockDim.x + threadIdx.x;
    if (i < ETOT) {
        int s, d;
        if (i < NE) {
            s = srcArr[i];
            d = dstArr[i];
        } else {
            s = d = i - NE;
        }
        int pos = atomicAdd(&cur[d], 1);
        csr[pos] = s;
    }
}

// -------- layer-1 aggregation: wave/dst; 2 edge-slots x 32 cg; pipelined ---
__global__ __launch_bounds__(256) void aggregate1(
        const int* __restrict__ offs, const int* __restrict__ csr,
        const __bf16* __restrict__ h, const float* __restrict__ alsrc,
        const float* __restrict__ aldst, const float* __restrict__ bias,
        __bf16* __restrict__ z) {
    int lane = threadIdx.x & 63, wid = threadIdx.x >> 6;
    int d = blockIdx.x * 4 + wid;
    if (d >= MPAD) return;
    int es = lane >> 5;        // edge slot 0..1
    int cg = lane & 31;        // channel group: 8 ch each
    if (d >= NN) {             // zero-fill padding rows (gemm2 reads them)
        if (es == 0) *(uint4*)(z + (size_t)d * ICH + cg * 8) = uint4{0u, 0u, 0u, 0u};
        return;
    }
    int head = cg >> 3;
    int e0 = offs[d], e1 = offs[d + 1];
    float ald = aldst[d * HEADS + head];
    float acc[8] = {};
    float wsum = 0.f;
    int e = e0 + es;
    // depth-2 software pipeline: stage A in flight
    int sA = (e < e1) ? csr[e] : 0;
    float alA = alsrc[sA * HEADS + head];
    v8bf hvA = *(const v8bf*)(h + (size_t)sA * ICH + cg * 8);
    for (; e < e1; e += 2) {
        int en = e + 2;
        int sB = (en < e1) ? csr[en] : 0;
        float alB = alsrc[sB * HEADS + head];
        v8bf hvB = *(const v8bf*)(h + (size_t)sB * ICH + cg * 8);
        float x = alA + ald;
        x = (x > 0.f) ? x : SLOPE * x;
        float w = __expf(x);
        wsum += w;
#pragma unroll
        for (int j = 0; j < 8; j++) acc[j] += w * (float)hvA[j];
        alA = alB; hvA = hvB;
    }
#pragma unroll
    for (int j = 0; j < 8; j++) acc[j] += __shfl_down(acc[j], 32, 64);
    wsum += __shfl_down(wsum, 32, 64);
    if (es == 0) {
        float inv = 1.f / (wsum + 1e-16f);
        union { __bf16 hh[8]; uint4 u; } p;
#pragma unroll
        for (int j = 0; j < 8; j++) {
            float o = acc[j] * inv + bias[cg * 8 + j];
            o = (o > 0.f) ? o : (__expf(o) - 1.f);  // ELU
            p.hh[j] = (__bf16)o;
        }
        *(uint4*)(z + (size_t)d * ICH + cg * 8) = p.u;
    }
}

// -------- layer-2 aggregation: wave/dst; 8 edge-slots x 8 cg; compact h2 ---
__global__ __launch_bounds__(256) void aggregate2(
        const int* __restrict__ offs, const int* __restrict__ csr,
        const __bf16* __restrict__ h2, const float* __restrict__ alsrc,
        const float* __restrict__ aldst, const float* __restrict__ bias,
        float* __restrict__ out) {
    int lane = threadIdx.x & 63, wid = threadIdx.x >> 6;
    int d = blockIdx.x * 4 + wid;
    if (d >= NN) return;
    int es = lane >> 3;        // edge slot 0..7
    int cg = lane & 7;         // channel group: 8 ch; cg<5 valid (40 ch)
    bool on = cg < 5;
    int cgc = on ? cg : 4;     // clamp for safe loads
    int e0 = offs[d], e1 = offs[d + 1];
    float ald = aldst[d];
    float acc[8] = {};
    float wsum = 0.f;
    int e = e0 + es;
    int sA = (e < e1) ? csr[e] : 0;
    float alA = alsrc[sA];
    v8bf hvA = *(const v8bf*)(h2 + (size_t)sA * OCH + cgc * 8);
    for (; e < e1; e += 8) {
        int en = e + 8;
        int sB = (en < e1) ? csr[en] : 0;
        float alB = alsrc[sB];
        v8bf hvB = *(const v8bf*)(h2 + (size_t)sB * OCH + cgc * 8);
        float x = alA + ald;
        x = (x > 0.f) ? x : SLOPE * x;
        float w = __expf(x);
        wsum += w;
#pragma unroll
        for (int j = 0; j < 8; j++) acc[j] += w * (float)hvA[j];
        alA = alB; hvA = hvB;
    }
#pragma unroll
    for (int m = 8; m <= 32; m <<= 1) {
#pragma unroll
        for (int j = 0; j < 8; j++) acc[j] += __shfl_xor(acc[j], m, 64);
        wsum += __shfl_xor(wsum, m, 64);
    }
    if (es == 0 && on) {
        float inv = 1.f / (wsum + 1e-16f);
#pragma unroll
        for (int j = 0; j < 8; j++)
            out[(size_t)d * OCH + cg * 8 + j] = acc[j] * inv + bias[cg * 8 + j];
    }
}

extern "C" void kernel_launch(void* const* d_in, const int* in_sizes, int n_in,
                              void* d_out, int out_size, void* d_ws, size_t ws_size,
                              hipStream_t stream) {
    const float* x   = (const float*)d_in[0];
    const int*   ei  = (const int*)d_in[1];
    const float* W1  = (const float*)d_in[2];
    const float* as1 = (const float*)d_in[3];
    const float* ad1 = (const float*)d_in[4];
    const float* b1  = (const float*)d_in[5];
    const float* W2  = (const float*)d_in[6];
    const float* as2 = (const float*)d_in[7];
    const float* ad2 = (const float*)d_in[8];
    const float* b2  = (const float*)d_in[9];
    float* out = (float*)d_out;

    char* ws = (char*)d_ws;
    size_t o = 0;
    auto alloc = [&](size_t bytes) {
        void* p = ws + o;
        o += (bytes + 255) & ~(size_t)255;
        return p;
    };
    __bf16* xb    = (__bf16*)alloc((size_t)MPAD * ICH * 2);
    __bf16* h1    = (__bf16*)alloc((size_t)MPAD * ICH * 2);
    __bf16* z     = (__bf16*)alloc((size_t)MPAD * ICH * 2);
    __bf16* h2    = (__bf16*)alloc((size_t)MPAD * OCH * 2);
    __bf16* W1T   = (__bf16*)alloc((size_t)256 * 256 * 2);
    __bf16* W2T   = (__bf16*)alloc((size_t)128 * 256 * 2);
    float* alsrc1 = (float*)alloc((size_t)NN * HEADS * 4);
    float* aldst1 = (float*)alloc((size_t)NN * HEADS * 4);
    float* alsrc2 = (float*)alloc((size_t)NN * 4);
    float* aldst2 = (float*)alloc((size_t)NN * 4);
    int*   deg    = (int*)alloc((size_t)NN * 4);
    int*   offs   = (int*)alloc((size_t)(NN + 1) * 4);
    int*   cur    = (int*)alloc((size_t)NN * 4);
    int*   csr    = (int*)alloc((size_t)ETOT * 4);
    int*   bsum   = (int*)alloc((size_t)SCAN_B * 4);
    int*   bexcl  = (int*)alloc((size_t)SCAN_B * 4);

    const int* srcArr = ei;
    const int* dstArr = ei + NE;

    // CSR build (graph shared by both layers)
    hipMemsetAsync(deg, 0, (size_t)NN * 4, stream);
    hist_kernel<<<(ETOT + 255) / 256, 256, 0, stream>>>(dstArr, deg);
    blocksum_kernel<<<SCAN_B, 256, 0, stream>>>(deg, bsum);
    scan_bsum<<<1, 256, 0, stream>>>(bsum, bexcl);
    scan_final<<<SCAN_B, 256, 0, stream>>>(deg, bexcl, offs, cur);
    scatter_kernel<<<(ETOT + 255) / 256, 256, 0, stream>>>(srcArr, dstArr, cur, csr);

    // bf16 conversions (conv_pad also zero-fills padding rows)
    conv_pad<<<(MPAD * ICH / 4 + 255) / 256, 256, 0, stream>>>(x, xb);
    transW<<<(65536 + 32768) / 256, 256, 0, stream>>>(W1, W2, W1T, W2T);

    // Layer 1
    gemm_mfma<<<dim3(2, MPAD / 128), 256, 0, stream>>>(xb, W1T, h1, 256, 256);
    al1_kernel<<<(NN + 3) / 4, 256, 0, stream>>>(h1, as1, ad1, alsrc1, aldst1);
    aggregate1<<<MPAD / 4, 256, 0, stream>>>(offs, csr, h1, alsrc1, aldst1, b1, z);

    // Layer 2 (h2 compact: ldc = 40)
    gemm_mfma<<<dim3(1, MPAD / 128), 256, 0, stream>>>(z, W2T, h2, OCH, OCH);
    al2_kernel<<<4096, 64, 0, stream>>>(h2, as2, ad2, alsrc2, aldst2);
    aggregate2<<<(NN + 3) / 4, 256, 0, stream>>>(offs, csr, h2, alsrc2, aldst2, b2, out);
}

// Round 7
// 331.430 us; speedup vs baseline: 2.8089x; 1.0512x over previous
//
#include <hip/hip_runtime.h>

#define NN 50000
#define MPAD 50048   // 391 * 128
#define ICH 256
#define HID 64
#define HEADS 4
#define OCH 40
#define NE 800000
#define ETOT (NE + NN)
#define SLOPE 0.2f
#define LDP 40       // padded LDS row stride (bf16 elems): 32 data + 8 pad
#define SCAN_B 196   // 196 * 256 = 50176 >= NN

typedef __bf16 v8bf __attribute__((ext_vector_type(8)));
typedef float v4f __attribute__((ext_vector_type(4)));

// W1 [256][256] -> W1T [256][256] bf16 ; W2 [256][40] -> W2T [128][256] bf16
__global__ void transW(const float* __restrict__ W1, const float* __restrict__ W2,
                       __bf16* __restrict__ W1T, __bf16* __restrict__ W2T) {
    int i = blockIdx.x * blockDim.x + threadIdx.x;
    if (i < 65536) {
        int n = i >> 8, k = i & 255;
        W1T[n * 256 + k] = (__bf16)W1[k * 256 + n];
    } else {
        int j = i - 65536;  // 0..32767
        int n = j >> 8, k = j & 255;
        W2T[n * 256 + k] = (n < OCH) ? (__bf16)W2[k * OCH + n] : (__bf16)0.f;
    }
}

// ------ layer-1 GEMM: h1 = bf16(x) @ W1, fused fp32->bf16 A-staging + al ---
__global__ __launch_bounds__(256) void gemm1_fused(
        const float* __restrict__ X, const __bf16* __restrict__ B,
        __bf16* __restrict__ C, const float* __restrict__ a_s,
        const float* __restrict__ a_d, float* __restrict__ alsrc,
        float* __restrict__ aldst) {
    __shared__ __bf16 As[128 * LDP];
    __shared__ __bf16 Bs[128 * LDP];
    int tid = threadIdx.x;
    int lane = tid & 63, wid = tid >> 6;
    int quad = lane >> 4, l15 = lane & 15;
    int wm = (wid & 1) * 64, wn = (wid >> 1) * 64;
    long row0 = (long)blockIdx.y * 128;
    long col0 = (long)blockIdx.x * 128;
    int ar = tid >> 1, ah = tid & 1;  // A staging: row 0..127, 16-float half
    bool avalid = (row0 + ar) < NN;
    const float* xrow = X + (size_t)(row0 + ar) * ICH + ah * 16;
    v4f acc[4][4] = {};
    for (int k0 = 0; k0 < 256; k0 += 32) {
        // stage A: fp32 -> bf16 in-register
        union { __bf16 hh[16]; uint4 u[2]; } pk;
        if (avalid) {
            const float4* p = (const float4*)(xrow + k0);
            float4 f0 = p[0], f1 = p[1], f2 = p[2], f3 = p[3];
            pk.hh[0] = (__bf16)f0.x;  pk.hh[1] = (__bf16)f0.y;
            pk.hh[2] = (__bf16)f0.z;  pk.hh[3] = (__bf16)f0.w;
            pk.hh[4] = (__bf16)f1.x;  pk.hh[5] = (__bf16)f1.y;
            pk.hh[6] = (__bf16)f1.z;  pk.hh[7] = (__bf16)f1.w;
            pk.hh[8] = (__bf16)f2.x;  pk.hh[9] = (__bf16)f2.y;
            pk.hh[10] = (__bf16)f2.z; pk.hh[11] = (__bf16)f2.w;
            pk.hh[12] = (__bf16)f3.x; pk.hh[13] = (__bf16)f3.y;
            pk.hh[14] = (__bf16)f3.z; pk.hh[15] = (__bf16)f3.w;
        } else {
            pk.u[0] = uint4{0u, 0u, 0u, 0u};
            pk.u[1] = uint4{0u, 0u, 0u, 0u};
        }
        *(uint4*)(&As[ar * LDP + ah * 16]) = pk.u[0];
        *(uint4*)(&As[ar * LDP + ah * 16 + 8]) = pk.u[1];
        // stage B (bf16 passthrough)
#pragma unroll
        for (int i = tid; i < 512; i += 256) {
            int r = i >> 2, q = i & 3;
            *(uint4*)(&Bs[r * LDP + q * 8]) = *(const uint4*)(B + (col0 + r) * 256 + k0 + q * 8);
        }
        __syncthreads();
        v8bf af[4], bfr[4];
#pragma unroll
        for (int t = 0; t < 4; t++) {
            af[t]  = *(const v8bf*)(&As[(wm + t * 16 + l15) * LDP + quad * 8]);
            bfr[t] = *(const v8bf*)(&Bs[(wn + t * 16 + l15) * LDP + quad * 8]);
        }
#pragma unroll
        for (int mi = 0; mi < 4; mi++)
#pragma unroll
            for (int ni = 0; ni < 4; ni++)
                acc[mi][ni] = __builtin_amdgcn_mfma_f32_16x16x32_bf16(af[mi], bfr[ni], acc[mi][ni], 0, 0, 0);
        __syncthreads();
    }
    // C write (bf16 h1)
#pragma unroll
    for (int mi = 0; mi < 4; mi++)
#pragma unroll
        for (int ni = 0; ni < 4; ni++)
#pragma unroll
            for (int r = 0; r < 4; r++) {
                long row = row0 + wm + mi * 16 + quad * 4 + r;
                long col = col0 + wn + ni * 16 + l15;
                C[row * ICH + col] = (__bf16)acc[mi][ni][r];
            }
    // fused al1: this wave's 64 cols are exactly one head
    int head = (int)((col0 + wn) >> 6);
    float asv[4], adv[4];
#pragma unroll
    for (int ni = 0; ni < 4; ni++) {
        int c = (int)col0 + wn + ni * 16 + l15;
        asv[ni] = a_s[c];
        adv[ni] = a_d[c];
    }
#pragma unroll
    for (int mi = 0; mi < 4; mi++)
#pragma unroll
        for (int r = 0; r < 4; r++) {
            float vs = 0.f, vd = 0.f;
#pragma unroll
            for (int ni = 0; ni < 4; ni++) {
                vs += acc[mi][ni][r] * asv[ni];
                vd += acc[mi][ni][r] * adv[ni];
            }
#pragma unroll
            for (int m = 1; m <= 8; m <<= 1) {
                vs += __shfl_xor(vs, m, 64);
                vd += __shfl_xor(vd, m, 64);
            }
            long row = row0 + wm + mi * 16 + quad * 4 + r;
            if (l15 == 0 && row < NN) {
                alsrc[row * HEADS + head] = vs;
                aldst[row * HEADS + head] = vd;
            }
        }
}

// ------ layer-2 GEMM: h2 = z @ W2 (compact 40-col out) + fused al2 ---------
__global__ __launch_bounds__(256) void gemm2_fused(
        const __bf16* __restrict__ A, const __bf16* __restrict__ B,
        __bf16* __restrict__ C, const float* __restrict__ a_s,
        const float* __restrict__ a_d, float* __restrict__ alsrc,
        float* __restrict__ aldst) {
    __shared__ __bf16 As[128 * LDP];
    __shared__ __bf16 Bs[128 * LDP];
    int tid = threadIdx.x;
    int lane = tid & 63, wid = tid >> 6;
    int quad = lane >> 4, l15 = lane & 15;
    int wm = (wid & 1) * 64, wn = (wid >> 1) * 64;
    long row0 = (long)blockIdx.y * 128;
    v4f acc[4][4] = {};
    for (int k0 = 0; k0 < 256; k0 += 32) {
#pragma unroll
        for (int i = tid; i < 512; i += 256) {
            int r = i >> 2, q = i & 3;
            *(uint4*)(&As[r * LDP + q * 8]) = *(const uint4*)(A + (row0 + r) * 256 + k0 + q * 8);
            *(uint4*)(&Bs[r * LDP + q * 8]) = *(const uint4*)(B + (size_t)r * 256 + k0 + q * 8);
        }
        __syncthreads();
        v8bf af[4], bfr[4];
#pragma unroll
        for (int t = 0; t < 4; t++) {
            af[t]  = *(const v8bf*)(&As[(wm + t * 16 + l15) * LDP + quad * 8]);
            bfr[t] = *(const v8bf*)(&Bs[(wn + t * 16 + l15) * LDP + quad * 8]);
        }
#pragma unroll
        for (int mi = 0; mi < 4; mi++)
#pragma unroll
            for (int ni = 0; ni < 4; ni++)
                acc[mi][ni] = __builtin_amdgcn_mfma_f32_16x16x32_bf16(af[mi], bfr[ni], acc[mi][ni], 0, 0, 0);
        __syncthreads();
    }
    // C write: compact 40 cols
#pragma unroll
    for (int mi = 0; mi < 4; mi++)
#pragma unroll
        for (int ni = 0; ni < 4; ni++)
#pragma unroll
            for (int r = 0; r < 4; r++) {
                long row = row0 + wm + mi * 16 + quad * 4 + r;
                int col = wn + ni * 16 + l15;
                if (col < OCH) C[row * OCH + col] = (__bf16)acc[mi][ni][r];
            }
    // fused al2 (head 0 only; only wn==0 waves hold cols < 40)
    if (wn == 0) {
        float asv[4], adv[4];
#pragma unroll
        for (int ni = 0; ni < 4; ni++) {
            int c = ni * 16 + l15;
            bool on = c < OCH;
            asv[ni] = on ? a_s[c] : 0.f;
            adv[ni] = on ? a_d[c] : 0.f;
        }
#pragma unroll
        for (int mi = 0; mi < 4; mi++)
#pragma unroll
            for (int r = 0; r < 4; r++) {
                float vs = 0.f, vd = 0.f;
#pragma unroll
                for (int ni = 0; ni < 4; ni++) {
                    vs += acc[mi][ni][r] * asv[ni];
                    vd += acc[mi][ni][r] * adv[ni];
                }
#pragma unroll
                for (int m = 1; m <= 8; m <<= 1) {
                    vs += __shfl_xor(vs, m, 64);
                    vd += __shfl_xor(vd, m, 64);
                }
                long row = row0 + wm + mi * 16 + quad * 4 + r;
                if (l15 == 0 && row < NN) {
                    alsrc[row] = vs;
                    aldst[row] = vd;
                }
            }
    }
}

// ---------------- CSR build ----------------
__global__ void hist_kernel(const int* __restrict__ dstArr, int* __restrict__ deg) {
    int i = blockIdx.x * blockDim.x + threadIdx.x;
    if (i < ETOT) {
        int d = (i < NE) ? dstArr[i] : (i - NE);
        atomicAdd(&deg[d], 1);
    }
}

__device__ __forceinline__ int block_excl_scan(int v, int tid, int* wsum) {
    int lane = tid & 63, w = tid >> 6;
    int x = v;
#pragma unroll
    for (int off = 1; off < 64; off <<= 1) {
        int t = __shfl_up(x, off, 64);
        if (lane >= off) x += t;
    }
    if (lane == 63) wsum[w] = x;
    __syncthreads();
    int base = 0;
    for (int i = 0; i < w; i++) base += wsum[i];
    return base + x - v;
}

__global__ __launch_bounds__(256) void blocksum_kernel(const int* __restrict__ deg,
                                                       int* __restrict__ bsum) {
    __shared__ int wsum[4];
    int i = blockIdx.x * 256 + threadIdx.x;
    int v = (i < NN) ? deg[i] : 0;
#pragma unroll
    for (int m = 1; m <= 32; m <<= 1) v += __shfl_xor(v, m, 64);
    if ((threadIdx.x & 63) == 0) wsum[threadIdx.x >> 6] = v;
    __syncthreads();
    if (threadIdx.x == 0) bsum[blockIdx.x] = wsum[0] + wsum[1] + wsum[2] + wsum[3];
}

__global__ __launch_bounds__(256) void scan_bsum(const int* __restrict__ bsum,
                                                 int* __restrict__ bexcl) {
    __shared__ int wsum[4];
    int t = threadIdx.x;
    int v = (t < SCAN_B) ? bsum[t] : 0;
    int excl = block_excl_scan(v, t, wsum);
    if (t < SCAN_B) bexcl[t] = excl;
}

__global__ __launch_bounds__(256) void scan_final(const int* __restrict__ deg,
                                                  const int* __restrict__ bexcl,
                                                  int* __restrict__ offs,
                                                  int* __restrict__ cur) {
    __shared__ int wsum[4];
    int i = blockIdx.x * 256 + threadIdx.x;
    int v = (i < NN) ? deg[i] : 0;
    int excl = block_excl_scan(v, threadIdx.x, wsum) + bexcl[blockIdx.x];
    if (i < NN) {
        offs[i] = excl;
        cur[i] = excl;
        if (i == NN - 1) offs[NN] = excl + v;
    }
}

__global__ void scatter_kernel(const int* __restrict__ srcArr, const int* __restrict__ dstArr,
                               int* __restrict__ cur, int* __restrict__ csr) {
    int i = blockIdx.x * blockDim.x + threadIdx.x;
    if (i < ETOT) {
        int s, d;
        if (i < NE) {
            s = srcArr[i];
            d = dstArr[i];
        } else {
            s = d = i - NE;
        }
        int pos = atomicAdd(&cur[d], 1);
        csr[pos] = s;
    }
}

// -------- layer-1 aggregation: wave/dst; 2 edge-slots x 32 cg; pipelined ---
__global__ __launch_bounds__(256) void aggregate1(
        const int* __restrict__ offs, const int* __restrict__ csr,
        const __bf16* __restrict__ h, const float* __restrict__ alsrc,
        const float* __restrict__ aldst, const float* __restrict__ bias,
        __bf16* __restrict__ z) {
    int lane = threadIdx.x & 63, wid = threadIdx.x >> 6;
    int d = blockIdx.x * 4 + wid;
    if (d >= MPAD) return;
    int es = lane >> 5;        // edge slot 0..1
    int cg = lane & 31;        // channel group: 8 ch each
    if (d >= NN) {             // zero-fill padding rows (gemm2 reads them)
        if (es == 0) *(uint4*)(z + (size_t)d * ICH + cg * 8) = uint4{0u, 0u, 0u, 0u};
        return;
    }
    int head = cg >> 3;
    int e0 = offs[d], e1 = offs[d + 1];
    float ald = aldst[d * HEADS + head];
    float acc[8] = {};
    float wsum = 0.f;
    int e = e0 + es;
    int sA = (e < e1) ? csr[e] : 0;
    float alA = alsrc[sA * HEADS + head];
    v8bf hvA = *(const v8bf*)(h + (size_t)sA * ICH + cg * 8);
    for (; e < e1; e += 2) {
        int en = e + 2;
        int sB = (en < e1) ? csr[en] : 0;
        float alB = alsrc[sB * HEADS + head];
        v8bf hvB = *(const v8bf*)(h + (size_t)sB * ICH + cg * 8);
        float x = alA + ald;
        x = (x > 0.f) ? x : SLOPE * x;
        float w = __expf(x);
        wsum += w;
#pragma unroll
        for (int j = 0; j < 8; j++) acc[j] += w * (float)hvA[j];
        alA = alB; hvA = hvB;
    }
#pragma unroll
    for (int j = 0; j < 8; j++) acc[j] += __shfl_down(acc[j], 32, 64);
    wsum += __shfl_down(wsum, 32, 64);
    if (es == 0) {
        float inv = 1.f / (wsum + 1e-16f);
        union { __bf16 hh[8]; uint4 u; } p;
#pragma unroll
        for (int j = 0; j < 8; j++) {
            float o = acc[j] * inv + bias[cg * 8 + j];
            o = (o > 0.f) ? o : (__expf(o) - 1.f);  // ELU
            p.hh[j] = (__bf16)o;
        }
        *(uint4*)(z + (size_t)d * ICH + cg * 8) = p.u;
    }
}

// -------- layer-2 aggregation: wave/dst; 8 edge-slots x 8 cg; compact h2 ---
__global__ __launch_bounds__(256) void aggregate2(
        const int* __restrict__ offs, const int* __restrict__ csr,
        const __bf16* __restrict__ h2, const float* __restrict__ alsrc,
        const float* __restrict__ aldst, const float* __restrict__ bias,
        float* __restrict__ out) {
    int lane = threadIdx.x & 63, wid = threadIdx.x >> 6;
    int d = blockIdx.x * 4 + wid;
    if (d >= NN) return;
    int es = lane >> 3;        // edge slot 0..7
    int cg = lane & 7;         // channel group: 8 ch; cg<5 valid (40 ch)
    bool on = cg < 5;
    int cgc = on ? cg : 4;     // clamp for safe loads
    int e0 = offs[d], e1 = offs[d + 1];
    float ald = aldst[d];
    float acc[8] = {};
    float wsum = 0.f;
    int e = e0 + es;
    int sA = (e < e1) ? csr[e] : 0;
    float alA = alsrc[sA];
    v8bf hvA = *(const v8bf*)(h2 + (size_t)sA * OCH + cgc * 8);
    for (; e < e1; e += 8) {
        int en = e + 8;
        int sB = (en < e1) ? csr[en] : 0;
        float alB = alsrc[sB];
        v8bf hvB = *(const v8bf*)(h2 + (size_t)sB * OCH + cgc * 8);
        float x = alA + ald;
        x = (x > 0.f) ? x : SLOPE * x;
        float w = __expf(x);
        wsum += w;
#pragma unroll
        for (int j = 0; j < 8; j++) acc[j] += w * (float)hvA[j];
        alA = alB; hvA = hvB;
    }
#pragma unroll
    for (int m = 8; m <= 32; m <<= 1) {
#pragma unroll
        for (int j = 0; j < 8; j++) acc[j] += __shfl_xor(acc[j], m, 64);
        wsum += __shfl_xor(wsum, m, 64);
    }
    if (es == 0 && on) {
        float inv = 1.f / (wsum + 1e-16f);
#pragma unroll
        for (int j = 0; j < 8; j++)
            out[(size_t)d * OCH + cg * 8 + j] = acc[j] * inv + bias[cg * 8 + j];
    }
}

extern "C" void kernel_launch(void* const* d_in, const int* in_sizes, int n_in,
                              void* d_out, int out_size, void* d_ws, size_t ws_size,
                              hipStream_t stream) {
    const float* x   = (const float*)d_in[0];
    const int*   ei  = (const int*)d_in[1];
    const float* W1  = (const float*)d_in[2];
    const float* as1 = (const float*)d_in[3];
    const float* ad1 = (const float*)d_in[4];
    const float* b1  = (const float*)d_in[5];
    const float* W2  = (const float*)d_in[6];
    const float* as2 = (const float*)d_in[7];
    const float* ad2 = (const float*)d_in[8];
    const float* b2  = (const float*)d_in[9];
    float* out = (float*)d_out;

    char* ws = (char*)d_ws;
    size_t o = 0;
    auto alloc = [&](size_t bytes) {
        void* p = ws + o;
        o += (bytes + 255) & ~(size_t)255;
        return p;
    };
    __bf16* h1    = (__bf16*)alloc((size_t)MPAD * ICH * 2);
    __bf16* z     = (__bf16*)alloc((size_t)MPAD * ICH * 2);
    __bf16* h2    = (__bf16*)alloc((size_t)MPAD * OCH * 2);
    __bf16* W1T   = (__bf16*)alloc((size_t)256 * 256 * 2);
    __bf16* W2T   = (__bf16*)alloc((size_t)128 * 256 * 2);
    float* alsrc1 = (float*)alloc((size_t)NN * HEADS * 4);
    float* aldst1 = (float*)alloc((size_t)NN * HEADS * 4);
    float* alsrc2 = (float*)alloc((size_t)NN * 4);
    float* aldst2 = (float*)alloc((size_t)NN * 4);
    int*   deg    = (int*)alloc((size_t)NN * 4);
    int*   offs   = (int*)alloc((size_t)(NN + 1) * 4);
    int*   cur    = (int*)alloc((size_t)NN * 4);
    int*   csr    = (int*)alloc((size_t)ETOT * 4);
    int*   bsum   = (int*)alloc((size_t)SCAN_B * 4);
    int*   bexcl  = (int*)alloc((size_t)SCAN_B * 4);

    const int* srcArr = ei;
    const int* dstArr = ei + NE;

    // CSR build (graph shared by both layers)
    hipMemsetAsync(deg, 0, (size_t)NN * 4, stream);
    hist_kernel<<<(ETOT + 255) / 256, 256, 0, stream>>>(dstArr, deg);
    blocksum_kernel<<<SCAN_B, 256, 0, stream>>>(deg, bsum);
    scan_bsum<<<1, 256, 0, stream>>>(bsum, bexcl);
    scan_final<<<SCAN_B, 256, 0, stream>>>(deg, bexcl, offs, cur);
    scatter_kernel<<<(ETOT + 255) / 256, 256, 0, stream>>>(srcArr, dstArr, cur, csr);

    // weight prep
    transW<<<(65536 + 32768) / 256, 256, 0, stream>>>(W1, W2, W1T, W2T);

    // Layer 1 (conv + al1 fused into gemm)
    gemm1_fused<<<dim3(2, MPAD / 128), 256, 0, stream>>>(x, W1T, h1, as1, ad1, alsrc1, aldst1);
    aggregate1<<<MPAD / 4, 256, 0, stream>>>(offs, csr, h1, alsrc1, aldst1, b1, z);

    // Layer 2 (al2 fused into gemm; h2 compact 40 cols)
    gemm2_fused<<<dim3(1, MPAD / 128), 256, 0, stream>>>(z, W2T, h2, as2, ad2, alsrc2, aldst2);
    aggregate2<<<(NN + 3) / 4, 256, 0, stream>>>(offs, csr, h2, alsrc2, aldst2, b2, out);
}

// Round 8
// 304.289 us; speedup vs baseline: 3.0594x; 1.0892x over previous
//
#include <hip/hip_runtime.h>

#define NN 50000
#define MPAD 50048   // 391 * 128
#define ICH 256
#define HID 64
#define HEADS 4
#define OCH 40
#define NE 800000
#define ETOT (NE + NN)
#define SLOPE 0.2f
#define LDP 40       // padded LDS row stride (bf16 elems): 32 data + 8 pad
#define SCAN_B 196   // 196 * 256 = 50176 >= NN

typedef __bf16 v8bf __attribute__((ext_vector_type(8)));
typedef float v4f __attribute__((ext_vector_type(4)));

// W1 [256][256] -> W1T bf16 ; W2 [256][40] -> W2T [128][256] bf16 ; zero deg
__global__ void transW(const float* __restrict__ W1, const float* __restrict__ W2,
                       __bf16* __restrict__ W1T, __bf16* __restrict__ W2T,
                       int* __restrict__ deg) {
    int i = blockIdx.x * blockDim.x + threadIdx.x;
    if (i < NN) deg[i] = 0;
    if (i < 65536) {
        int n = i >> 8, k = i & 255;
        W1T[n * 256 + k] = (__bf16)W1[k * 256 + n];
    } else {
        int j = i - 65536;  // 0..32767
        int n = j >> 8, k = j & 255;
        W2T[n * 256 + k] = (n < OCH) ? (__bf16)W2[k * OCH + n] : (__bf16)0.f;
    }
}

// ---- layer-1 GEMM: h1 = bf16(x)@W1, all 256 cols per block (x read once),
//      fused fp32->bf16 staging + al1 epilogue -------------------------------
__global__ __launch_bounds__(256) void gemm1_fused(
        const float* __restrict__ X, const __bf16* __restrict__ B,
        __bf16* __restrict__ C, const float* __restrict__ a_s,
        const float* __restrict__ a_d, float* __restrict__ alsrc,
        float* __restrict__ aldst) {
    __shared__ __bf16 As[128 * LDP];
    __shared__ __bf16 Bs0[128 * LDP];
    __shared__ __bf16 Bs1[128 * LDP];
    int tid = threadIdx.x;
    int lane = tid & 63, wid = tid >> 6;
    int quad = lane >> 4, l15 = lane & 15;
    int wm = (wid & 1) * 64, wn2 = (wid >> 1) * 64;  // col-within-half
    long row0 = (long)blockIdx.y * 128;
    v4f acc[2][4][4] = {};
    for (int k0 = 0; k0 < 256; k0 += 32) {
#pragma unroll
        for (int i = tid; i < 1536; i += 256) {
            if (i < 512) {               // A: fp32 -> bf16
                int r = i >> 2, q = i & 3;
                long row = row0 + r;
                union { __bf16 hh[8]; uint4 u; } pk;
                if (row < NN) {
                    const float4* p = (const float4*)(X + row * ICH + k0 + q * 8);
                    float4 f0 = p[0], f1 = p[1];
                    pk.hh[0] = (__bf16)f0.x; pk.hh[1] = (__bf16)f0.y;
                    pk.hh[2] = (__bf16)f0.z; pk.hh[3] = (__bf16)f0.w;
                    pk.hh[4] = (__bf16)f1.x; pk.hh[5] = (__bf16)f1.y;
                    pk.hh[6] = (__bf16)f1.z; pk.hh[7] = (__bf16)f1.w;
                } else {
                    pk.u = uint4{0u, 0u, 0u, 0u};
                }
                *(uint4*)(&As[r * LDP + q * 8]) = pk.u;
            } else if (i < 1024) {       // B cols 0..127
                int j = i - 512;
                int r = j >> 2, q = j & 3;
                *(uint4*)(&Bs0[r * LDP + q * 8]) = *(const uint4*)(B + (size_t)r * 256 + k0 + q * 8);
            } else {                     // B cols 128..255
                int j = i - 1024;
                int r = j >> 2, q = j & 3;
                *(uint4*)(&Bs1[r * LDP + q * 8]) = *(const uint4*)(B + (size_t)(128 + r) * 256 + k0 + q * 8);
            }
        }
        __syncthreads();
        v8bf af[4], bfr[2][4];
#pragma unroll
        for (int t = 0; t < 4; t++) {
            af[t]     = *(const v8bf*)(&As[(wm + t * 16 + l15) * LDP + quad * 8]);
            bfr[0][t] = *(const v8bf*)(&Bs0[(wn2 + t * 16 + l15) * LDP + quad * 8]);
            bfr[1][t] = *(const v8bf*)(&Bs1[(wn2 + t * 16 + l15) * LDP + quad * 8]);
        }
#pragma unroll
        for (int c = 0; c < 2; c++)
#pragma unroll
            for (int mi = 0; mi < 4; mi++)
#pragma unroll
                for (int ni = 0; ni < 4; ni++)
                    acc[c][mi][ni] = __builtin_amdgcn_mfma_f32_16x16x32_bf16(af[mi], bfr[c][ni], acc[c][mi][ni], 0, 0, 0);
        __syncthreads();
    }
    // C write + fused al1 (each (c) spans one head: 64 consecutive cols)
#pragma unroll
    for (int c = 0; c < 2; c++) {
        int colbase = c * 128 + wn2;
#pragma unroll
        for (int mi = 0; mi < 4; mi++)
#pragma unroll
            for (int ni = 0; ni < 4; ni++)
#pragma unroll
                for (int r = 0; r < 4; r++) {
                    long row = row0 + wm + mi * 16 + quad * 4 + r;
                    C[row * ICH + colbase + ni * 16 + l15] = (__bf16)acc[c][mi][ni][r];
                }
        int head = colbase >> 6;
        float asv[4], adv[4];
#pragma unroll
        for (int ni = 0; ni < 4; ni++) {
            int cc = colbase + ni * 16 + l15;
            asv[ni] = a_s[cc];
            adv[ni] = a_d[cc];
        }
#pragma unroll
        for (int mi = 0; mi < 4; mi++)
#pragma unroll
            for (int r = 0; r < 4; r++) {
                float vs = 0.f, vd = 0.f;
#pragma unroll
                for (int ni = 0; ni < 4; ni++) {
                    vs += acc[c][mi][ni][r] * asv[ni];
                    vd += acc[c][mi][ni][r] * adv[ni];
                }
#pragma unroll
                for (int m = 1; m <= 8; m <<= 1) {
                    vs += __shfl_xor(vs, m, 64);
                    vd += __shfl_xor(vd, m, 64);
                }
                long row = row0 + wm + mi * 16 + quad * 4 + r;
                if (l15 == 0 && row < NN) {
                    alsrc[row * HEADS + head] = vs;
                    aldst[row * HEADS + head] = vd;
                }
            }
    }
}

// ------ layer-2 GEMM: h2 = z @ W2 (compact 40-col out) + fused al2 ---------
__global__ __launch_bounds__(256) void gemm2_fused(
        const __bf16* __restrict__ A, const __bf16* __restrict__ B,
        __bf16* __restrict__ C, const float* __restrict__ a_s,
        const float* __restrict__ a_d, float* __restrict__ alsrc,
        float* __restrict__ aldst) {
    __shared__ __bf16 As[128 * LDP];
    __shared__ __bf16 Bs[128 * LDP];
    int tid = threadIdx.x;
    int lane = tid & 63, wid = tid >> 6;
    int quad = lane >> 4, l15 = lane & 15;
    int wm = (wid & 1) * 64, wn = (wid >> 1) * 64;
    long row0 = (long)blockIdx.y * 128;
    v4f acc[4][4] = {};
    for (int k0 = 0; k0 < 256; k0 += 32) {
#pragma unroll
        for (int i = tid; i < 512; i += 256) {
            int r = i >> 2, q = i & 3;
            *(uint4*)(&As[r * LDP + q * 8]) = *(const uint4*)(A + (row0 + r) * 256 + k0 + q * 8);
            *(uint4*)(&Bs[r * LDP + q * 8]) = *(const uint4*)(B + (size_t)r * 256 + k0 + q * 8);
        }
        __syncthreads();
        v8bf af[4], bfr[4];
#pragma unroll
        for (int t = 0; t < 4; t++) {
            af[t]  = *(const v8bf*)(&As[(wm + t * 16 + l15) * LDP + quad * 8]);
            bfr[t] = *(const v8bf*)(&Bs[(wn + t * 16 + l15) * LDP + quad * 8]);
        }
#pragma unroll
        for (int mi = 0; mi < 4; mi++)
#pragma unroll
            for (int ni = 0; ni < 4; ni++)
                acc[mi][ni] = __builtin_amdgcn_mfma_f32_16x16x32_bf16(af[mi], bfr[ni], acc[mi][ni], 0, 0, 0);
        __syncthreads();
    }
#pragma unroll
    for (int mi = 0; mi < 4; mi++)
#pragma unroll
        for (int ni = 0; ni < 4; ni++)
#pragma unroll
            for (int r = 0; r < 4; r++) {
                long row = row0 + wm + mi * 16 + quad * 4 + r;
                int col = wn + ni * 16 + l15;
                if (col < OCH) C[row * OCH + col] = (__bf16)acc[mi][ni][r];
            }
    if (wn == 0) {
        float asv[4], adv[4];
#pragma unroll
        for (int ni = 0; ni < 4; ni++) {
            int c = ni * 16 + l15;
            bool on = c < OCH;
            asv[ni] = on ? a_s[c] : 0.f;
            adv[ni] = on ? a_d[c] : 0.f;
        }
#pragma unroll
        for (int mi = 0; mi < 4; mi++)
#pragma unroll
            for (int r = 0; r < 4; r++) {
                float vs = 0.f, vd = 0.f;
#pragma unroll
                for (int ni = 0; ni < 4; ni++) {
                    vs += acc[mi][ni][r] * asv[ni];
                    vd += acc[mi][ni][r] * adv[ni];
                }
#pragma unroll
                for (int m = 1; m <= 8; m <<= 1) {
                    vs += __shfl_xor(vs, m, 64);
                    vd += __shfl_xor(vd, m, 64);
                }
                long row = row0 + wm + mi * 16 + quad * 4 + r;
                if (l15 == 0 && row < NN) {
                    alsrc[row] = vs;
                    aldst[row] = vd;
                }
            }
    }
}

// ---------------- CSR build ----------------
// hist also records each edge's rank within its dst bucket (the atomic's
// return value) so scatter needs no second atomic.
__global__ void hist_kernel(const int* __restrict__ dstArr, int* __restrict__ deg,
                            int* __restrict__ rank) {
    int i = blockIdx.x * blockDim.x + threadIdx.x;
    if (i < ETOT) {
        int d = (i < NE) ? dstArr[i] : (i - NE);
        rank[i] = atomicAdd(&deg[d], 1);
    }
}

__global__ __launch_bounds__(256) void blocksum_kernel(const int* __restrict__ deg,
                                                       int* __restrict__ bsum) {
    __shared__ int wsum[4];
    int i = blockIdx.x * 256 + threadIdx.x;
    int v = (i < NN) ? deg[i] : 0;
#pragma unroll
    for (int m = 1; m <= 32; m <<= 1) v += __shfl_xor(v, m, 64);
    if ((threadIdx.x & 63) == 0) wsum[threadIdx.x >> 6] = v;
    __syncthreads();
    if (threadIdx.x == 0) bsum[blockIdx.x] = wsum[0] + wsum[1] + wsum[2] + wsum[3];
}

// base-reduction + element scan in one kernel (replaces scan_bsum+scan_final)
__global__ __launch_bounds__(256) void scan_final(const int* __restrict__ deg,
                                                  const int* __restrict__ bsum,
                                                  int* __restrict__ offs) {
    __shared__ int wsum[4];
    int t = threadIdx.x;
    int lane = t & 63, w = t >> 6;
    // block base = sum of bsum[0 .. blockIdx.x-1]
    int pv = (t < blockIdx.x) ? bsum[t] : 0;  // blockIdx.x <= 195 < 256
#pragma unroll
    for (int m = 1; m <= 32; m <<= 1) pv += __shfl_xor(pv, m, 64);
    if (lane == 0) wsum[w] = pv;
    __syncthreads();
    int base = wsum[0] + wsum[1] + wsum[2] + wsum[3];
    __syncthreads();  // wsum reused below
    // element-wise exclusive scan within block
    int i = blockIdx.x * 256 + t;
    int v = (i < NN) ? deg[i] : 0;
    int x = v;
#pragma unroll
    for (int off = 1; off < 64; off <<= 1) {
        int tt = __shfl_up(x, off, 64);
        if (lane >= off) x += tt;
    }
    if (lane == 63) wsum[w] = x;
    __syncthreads();
    int wbase = 0;
    for (int k = 0; k < w; k++) wbase += wsum[k];
    int excl = base + wbase + x - v;
    if (i < NN) {
        offs[i] = excl;
        if (i == NN - 1) offs[NN] = excl + v;
    }
}

__global__ void scatter_kernel(const int* __restrict__ srcArr, const int* __restrict__ dstArr,
                               const int* __restrict__ offs, const int* __restrict__ rank,
                               int* __restrict__ csr) {
    int i = blockIdx.x * blockDim.x + threadIdx.x;
    if (i < ETOT) {
        int s, d;
        if (i < NE) {
            s = srcArr[i];
            d = dstArr[i];
        } else {
            s = d = i - NE;
        }
        csr[offs[d] + rank[i]] = s;
    }
}

// -------- layer-1 aggregation: wave/dst; 2 edge-slots x 32 cg; pipelined ---
__global__ __launch_bounds__(256) void aggregate1(
        const int* __restrict__ offs, const int* __restrict__ csr,
        const __bf16* __restrict__ h, const float* __restrict__ alsrc,
        const float* __restrict__ aldst, const float* __restrict__ bias,
        __bf16* __restrict__ z) {
    int lane = threadIdx.x & 63, wid = threadIdx.x >> 6;
    int d = blockIdx.x * 4 + wid;
    if (d >= MPAD) return;
    int es = lane >> 5;        // edge slot 0..1
    int cg = lane & 31;        // channel group: 8 ch each
    if (d >= NN) {             // zero-fill padding rows (gemm2 reads them)
        if (es == 0) *(uint4*)(z + (size_t)d * ICH + cg * 8) = uint4{0u, 0u, 0u, 0u};
        return;
    }
    int head = cg >> 3;
    int e0 = offs[d], e1 = offs[d + 1];
    float ald = aldst[d * HEADS + head];
    float acc[8] = {};
    float wsum = 0.f;
    int e = e0 + es;
    int sA = (e < e1) ? csr[e] : 0;
    float alA = alsrc[sA * HEADS + head];
    v8bf hvA = *(const v8bf*)(h + (size_t)sA * ICH + cg * 8);
    for (; e < e1; e += 2) {
        int en = e + 2;
        int sB = (en < e1) ? csr[en] : 0;
        float alB = alsrc[sB * HEADS + head];
        v8bf hvB = *(const v8bf*)(h + (size_t)sB * ICH + cg * 8);
        float x = alA + ald;
        x = (x > 0.f) ? x : SLOPE * x;
        float w = __expf(x);
        wsum += w;
#pragma unroll
        for (int j = 0; j < 8; j++) acc[j] += w * (float)hvA[j];
        alA = alB; hvA = hvB;
    }
#pragma unroll
    for (int j = 0; j < 8; j++) acc[j] += __shfl_down(acc[j], 32, 64);
    wsum += __shfl_down(wsum, 32, 64);
    if (es == 0) {
        float inv = 1.f / (wsum + 1e-16f);
        union { __bf16 hh[8]; uint4 u; } p;
#pragma unroll
        for (int j = 0; j < 8; j++) {
            float o = acc[j] * inv + bias[cg * 8 + j];
            o = (o > 0.f) ? o : (__expf(o) - 1.f);  // ELU
            p.hh[j] = (__bf16)o;
        }
        *(uint4*)(z + (size_t)d * ICH + cg * 8) = p.u;
    }
}

// -------- layer-2 aggregation: wave/dst; 8 edge-slots x 8 cg; compact h2 ---
__global__ __launch_bounds__(256) void aggregate2(
        const int* __restrict__ offs, const int* __restrict__ csr,
        const __bf16* __restrict__ h2, const float* __restrict__ alsrc,
        const float* __restrict__ aldst, const float* __restrict__ bias,
        float* __restrict__ out) {
    int lane = threadIdx.x & 63, wid = threadIdx.x >> 6;
    int d = blockIdx.x * 4 + wid;
    if (d >= NN) return;
    int es = lane >> 3;        // edge slot 0..7
    int cg = lane & 7;         // channel group: 8 ch; cg<5 valid (40 ch)
    bool on = cg < 5;
    int cgc = on ? cg : 4;     // clamp for safe loads
    int e0 = offs[d], e1 = offs[d + 1];
    float ald = aldst[d];
    float acc[8] = {};
    float wsum = 0.f;
    int e = e0 + es;
    int sA = (e < e1) ? csr[e] : 0;
    float alA = alsrc[sA];
    v8bf hvA = *(const v8bf*)(h2 + (size_t)sA * OCH + cgc * 8);
    for (; e < e1; e += 8) {
        int en = e + 8;
        int sB = (en < e1) ? csr[en] : 0;
        float alB = alsrc[sB];
        v8bf hvB = *(const v8bf*)(h2 + (size_t)sB * OCH + cgc * 8);
        float x = alA + ald;
        x = (x > 0.f) ? x : SLOPE * x;
        float w = __expf(x);
        wsum += w;
#pragma unroll
        for (int j = 0; j < 8; j++) acc[j] += w * (float)hvA[j];
        alA = alB; hvA = hvB;
    }
#pragma unroll
    for (int m = 8; m <= 32; m <<= 1) {
#pragma unroll
        for (int j = 0; j < 8; j++) acc[j] += __shfl_xor(acc[j], m, 64);
        wsum += __shfl_xor(wsum, m, 64);
    }
    if (es == 0 && on) {
        float inv = 1.f / (wsum + 1e-16f);
#pragma unroll
        for (int j = 0; j < 8; j++)
            out[(size_t)d * OCH + cg * 8 + j] = acc[j] * inv + bias[cg * 8 + j];
    }
}

extern "C" void kernel_launch(void* const* d_in, const int* in_sizes, int n_in,
                              void* d_out, int out_size, void* d_ws, size_t ws_size,
                              hipStream_t stream) {
    const float* x   = (const float*)d_in[0];
    const int*   ei  = (const int*)d_in[1];
    const float* W1  = (const float*)d_in[2];
    const float* as1 = (const float*)d_in[3];
    const float* ad1 = (const float*)d_in[4];
    const float* b1  = (const float*)d_in[5];
    const float* W2  = (const float*)d_in[6];
    const float* as2 = (const float*)d_in[7];
    const float* ad2 = (const float*)d_in[8];
    const float* b2  = (const float*)d_in[9];
    float* out = (float*)d_out;

    char* ws = (char*)d_ws;
    size_t o = 0;
    auto alloc = [&](size_t bytes) {
        void* p = ws + o;
        o += (bytes + 255) & ~(size_t)255;
        return p;
    };
    __bf16* h1    = (__bf16*)alloc((size_t)MPAD * ICH * 2);
    __bf16* z     = (__bf16*)alloc((size_t)MPAD * ICH * 2);
    __bf16* h2    = (__bf16*)alloc((size_t)MPAD * OCH * 2);
    __bf16* W1T   = (__bf16*)alloc((size_t)256 * 256 * 2);
    __bf16* W2T   = (__bf16*)alloc((size_t)128 * 256 * 2);
    float* alsrc1 = (float*)alloc((size_t)NN * HEADS * 4);
    float* aldst1 = (float*)alloc((size_t)NN * HEADS * 4);
    float* alsrc2 = (float*)alloc((size_t)NN * 4);
    float* aldst2 = (float*)alloc((size_t)NN * 4);
    int*   deg    = (int*)alloc((size_t)NN * 4);
    int*   offs   = (int*)alloc((size_t)(NN + 1) * 4);
    int*   csr    = (int*)alloc((size_t)ETOT * 4);
    int*   rank   = (int*)alloc((size_t)ETOT * 4);
    int*   bsum   = (int*)alloc((size_t)SCAN_B * 4);

    const int* srcArr = ei;
    const int* dstArr = ei + NE;

    // weight prep + deg zeroing (must precede hist)
    transW<<<(65536 + 32768) / 256, 256, 0, stream>>>(W1, W2, W1T, W2T, deg);

    // CSR build (graph shared by both layers); hist emits per-edge rank
    hist_kernel<<<(ETOT + 255) / 256, 256, 0, stream>>>(dstArr, deg, rank);
    blocksum_kernel<<<SCAN_B, 256, 0, stream>>>(deg, bsum);
    scan_final<<<SCAN_B, 256, 0, stream>>>(deg, bsum, offs);
    scatter_kernel<<<(ETOT + 255) / 256, 256, 0, stream>>>(srcArr, dstArr, offs, rank, csr);

    // Layer 1 (conv + al1 fused into gemm; x read once)
    gemm1_fused<<<dim3(1, MPAD / 128), 256, 0, stream>>>(x, W1T, h1, as1, ad1, alsrc1, aldst1);
    aggregate1<<<MPAD / 4, 256, 0, stream>>>(offs, csr, h1, alsrc1, aldst1, b1, z);

    // Layer 2 (al2 fused into gemm; h2 compact 40 cols)
    gemm2_fused<<<dim3(1, MPAD / 128), 256, 0, stream>>>(z, W2T, h2, as2, ad2, alsrc2, aldst2);
    aggregate2<<<(NN + 3) / 4, 256, 0, stream>>>(offs, csr, h2, alsrc2, aldst2, b2, out);
}

// Round 9
// 302.536 us; speedup vs baseline: 3.0771x; 1.0058x over previous
//
#include <hip/hip_runtime.h>

#define NN 50000
#define MPAD 50048   // 391 * 128
#define ICH 256
#define HID 64
#define HEADS 4
#define OCH 40
#define NE 800000
#define ETOT (NE + NN)
#define SLOPE 0.2f
#define LDP 40       // padded LDS row stride (bf16 elems): 32 data + 8 pad
#define SCAN_B 196   // 196 * 256 = 50176 >= NN
#define GB1 (MPAD / 128)          // 391 gemm1 blocks
#define HB ((ETOT + 255) / 256)   // 3321 edge blocks

typedef __bf16 v8bf __attribute__((ext_vector_type(8)));
typedef float v4f __attribute__((ext_vector_type(4)));

// ---- prep: blocks [0,384) transpose W1/W2 to bf16; blocks [384, ...) hist --
// deg must be zeroed (memset) BEFORE this kernel.
__global__ __launch_bounds__(256) void prep_kernel(
        const float* __restrict__ W1, const float* __restrict__ W2,
        __bf16* __restrict__ W1T, __bf16* __restrict__ W2T,
        const int* __restrict__ dstArr, int* __restrict__ deg,
        int* __restrict__ rank) {
    int blk = blockIdx.x;
    if (blk < 384) {
        int i = blk * 256 + threadIdx.x;  // 0..98303
        if (i < 65536) {
            int n = i >> 8, k = i & 255;
            W1T[n * 256 + k] = (__bf16)W1[k * 256 + n];
        } else {
            int j = i - 65536;  // 0..32767
            int n = j >> 8, k = j & 255;
            W2T[n * 256 + k] = (n < OCH) ? (__bf16)W2[k * OCH + n] : (__bf16)0.f;
        }
    } else {
        int i = (blk - 384) * 256 + threadIdx.x;
        if (i < ETOT) {
            int d = (i < NE) ? dstArr[i] : (i - NE);
            rank[i] = atomicAdd(&deg[d], 1);
        }
    }
}

__global__ __launch_bounds__(256) void blocksum_kernel(const int* __restrict__ deg,
                                                       int* __restrict__ bsum) {
    __shared__ int wsum[4];
    int i = blockIdx.x * 256 + threadIdx.x;
    int v = (i < NN) ? deg[i] : 0;
#pragma unroll
    for (int m = 1; m <= 32; m <<= 1) v += __shfl_xor(v, m, 64);
    if ((threadIdx.x & 63) == 0) wsum[threadIdx.x >> 6] = v;
    __syncthreads();
    if (threadIdx.x == 0) bsum[blockIdx.x] = wsum[0] + wsum[1] + wsum[2] + wsum[3];
}

// base-reduction + element scan in one kernel
__global__ __launch_bounds__(256) void scan_final(const int* __restrict__ deg,
                                                  const int* __restrict__ bsum,
                                                  int* __restrict__ offs) {
    __shared__ int wsum[4];
    int t = threadIdx.x;
    int lane = t & 63, w = t >> 6;
    int pv = (t < blockIdx.x) ? bsum[t] : 0;  // blockIdx.x <= 195 < 256
#pragma unroll
    for (int m = 1; m <= 32; m <<= 1) pv += __shfl_xor(pv, m, 64);
    if (lane == 0) wsum[w] = pv;
    __syncthreads();
    int base = wsum[0] + wsum[1] + wsum[2] + wsum[3];
    __syncthreads();
    int i = blockIdx.x * 256 + t;
    int v = (i < NN) ? deg[i] : 0;
    int x = v;
#pragma unroll
    for (int off = 1; off < 64; off <<= 1) {
        int tt = __shfl_up(x, off, 64);
        if (lane >= off) x += tt;
    }
    if (lane == 63) wsum[w] = x;
    __syncthreads();
    int wbase = 0;
    for (int k = 0; k < w; k++) wbase += wsum[k];
    int excl = base + wbase + x - v;
    if (i < NN) {
        offs[i] = excl;
        if (i == NN - 1) offs[NN] = excl + v;
    }
}

// ---- fused: blocks [0,GB1) = layer-1 GEMM (+bf16 staging + al1 epilogue);
//      blocks [GB1, GB1+HB) = CSR scatter (independent work, co-scheduled) ---
__global__ __launch_bounds__(256) void gemm1_scatter(
        const float* __restrict__ X, const __bf16* __restrict__ B,
        __bf16* __restrict__ C, const float* __restrict__ a_s,
        const float* __restrict__ a_d, float* __restrict__ alsrc,
        float* __restrict__ aldst,
        const int* __restrict__ srcArr, const int* __restrict__ dstArr,
        const int* __restrict__ offs, const int* __restrict__ rank,
        int* __restrict__ csr) {
    if (blockIdx.x >= GB1) {
        // ---------- scatter branch ----------
        int i = (blockIdx.x - GB1) * 256 + threadIdx.x;
        if (i < ETOT) {
            int s, d;
            if (i < NE) {
                s = srcArr[i];
                d = dstArr[i];
            } else {
                s = d = i - NE;
            }
            csr[offs[d] + rank[i]] = s;
        }
        return;
    }
    // ---------- gemm1 branch ----------
    __shared__ __bf16 As[128 * LDP];
    __shared__ __bf16 Bs0[128 * LDP];
    __shared__ __bf16 Bs1[128 * LDP];
    int tid = threadIdx.x;
    int lane = tid & 63, wid = tid >> 6;
    int quad = lane >> 4, l15 = lane & 15;
    int wm = (wid & 1) * 64, wn2 = (wid >> 1) * 64;
    long row0 = (long)blockIdx.x * 128;
    v4f acc[2][4][4] = {};
    for (int k0 = 0; k0 < 256; k0 += 32) {
#pragma unroll
        for (int i = tid; i < 1536; i += 256) {
            if (i < 512) {               // A: fp32 -> bf16
                int r = i >> 2, q = i & 3;
                long row = row0 + r;
                union { __bf16 hh[8]; uint4 u; } pk;
                if (row < NN) {
                    const float4* p = (const float4*)(X + row * ICH + k0 + q * 8);
                    float4 f0 = p[0], f1 = p[1];
                    pk.hh[0] = (__bf16)f0.x; pk.hh[1] = (__bf16)f0.y;
                    pk.hh[2] = (__bf16)f0.z; pk.hh[3] = (__bf16)f0.w;
                    pk.hh[4] = (__bf16)f1.x; pk.hh[5] = (__bf16)f1.y;
                    pk.hh[6] = (__bf16)f1.z; pk.hh[7] = (__bf16)f1.w;
                } else {
                    pk.u = uint4{0u, 0u, 0u, 0u};
                }
                *(uint4*)(&As[r * LDP + q * 8]) = pk.u;
            } else if (i < 1024) {
                int j = i - 512;
                int r = j >> 2, q = j & 3;
                *(uint4*)(&Bs0[r * LDP + q * 8]) = *(const uint4*)(B + (size_t)r * 256 + k0 + q * 8);
            } else {
                int j = i - 1024;
                int r = j >> 2, q = j & 3;
                *(uint4*)(&Bs1[r * LDP + q * 8]) = *(const uint4*)(B + (size_t)(128 + r) * 256 + k0 + q * 8);
            }
        }
        __syncthreads();
        v8bf af[4], bfr[2][4];
#pragma unroll
        for (int t = 0; t < 4; t++) {
            af[t]     = *(const v8bf*)(&As[(wm + t * 16 + l15) * LDP + quad * 8]);
            bfr[0][t] = *(const v8bf*)(&Bs0[(wn2 + t * 16 + l15) * LDP + quad * 8]);
            bfr[1][t] = *(const v8bf*)(&Bs1[(wn2 + t * 16 + l15) * LDP + quad * 8]);
        }
#pragma unroll
        for (int c = 0; c < 2; c++)
#pragma unroll
            for (int mi = 0; mi < 4; mi++)
#pragma unroll
                for (int ni = 0; ni < 4; ni++)
                    acc[c][mi][ni] = __builtin_amdgcn_mfma_f32_16x16x32_bf16(af[mi], bfr[c][ni], acc[c][mi][ni], 0, 0, 0);
        __syncthreads();
    }
#pragma unroll
    for (int c = 0; c < 2; c++) {
        int colbase = c * 128 + wn2;
#pragma unroll
        for (int mi = 0; mi < 4; mi++)
#pragma unroll
            for (int ni = 0; ni < 4; ni++)
#pragma unroll
                for (int r = 0; r < 4; r++) {
                    long row = row0 + wm + mi * 16 + quad * 4 + r;
                    C[row * ICH + colbase + ni * 16 + l15] = (__bf16)acc[c][mi][ni][r];
                }
        int head = colbase >> 6;
        float asv[4], adv[4];
#pragma unroll
        for (int ni = 0; ni < 4; ni++) {
            int cc = colbase + ni * 16 + l15;
            asv[ni] = a_s[cc];
            adv[ni] = a_d[cc];
        }
#pragma unroll
        for (int mi = 0; mi < 4; mi++)
#pragma unroll
            for (int r = 0; r < 4; r++) {
                float vs = 0.f, vd = 0.f;
#pragma unroll
                for (int ni = 0; ni < 4; ni++) {
                    vs += acc[c][mi][ni][r] * asv[ni];
                    vd += acc[c][mi][ni][r] * adv[ni];
                }
#pragma unroll
                for (int m = 1; m <= 8; m <<= 1) {
                    vs += __shfl_xor(vs, m, 64);
                    vd += __shfl_xor(vd, m, 64);
                }
                long row = row0 + wm + mi * 16 + quad * 4 + r;
                if (l15 == 0 && row < NN) {
                    alsrc[row * HEADS + head] = vs;
                    aldst[row * HEADS + head] = vd;
                }
            }
    }
}

// ------ layer-2 GEMM: h2 = z @ W2 (compact 40-col out) + fused al2 ---------
__global__ __launch_bounds__(256) void gemm2_fused(
        const __bf16* __restrict__ A, const __bf16* __restrict__ B,
        __bf16* __restrict__ C, const float* __restrict__ a_s,
        const float* __restrict__ a_d, float* __restrict__ alsrc,
        float* __restrict__ aldst) {
    __shared__ __bf16 As[128 * LDP];
    __shared__ __bf16 Bs[128 * LDP];
    int tid = threadIdx.x;
    int lane = tid & 63, wid = tid >> 6;
    int quad = lane >> 4, l15 = lane & 15;
    int wm = (wid & 1) * 64, wn = (wid >> 1) * 64;
    long row0 = (long)blockIdx.y * 128;
    v4f acc[4][4] = {};
    for (int k0 = 0; k0 < 256; k0 += 32) {
#pragma unroll
        for (int i = tid; i < 512; i += 256) {
            int r = i >> 2, q = i & 3;
            *(uint4*)(&As[r * LDP + q * 8]) = *(const uint4*)(A + (row0 + r) * 256 + k0 + q * 8);
            *(uint4*)(&Bs[r * LDP + q * 8]) = *(const uint4*)(B + (size_t)r * 256 + k0 + q * 8);
        }
        __syncthreads();
        v8bf af[4], bfr[4];
#pragma unroll
        for (int t = 0; t < 4; t++) {
            af[t]  = *(const v8bf*)(&As[(wm + t * 16 + l15) * LDP + quad * 8]);
            bfr[t] = *(const v8bf*)(&Bs[(wn + t * 16 + l15) * LDP + quad * 8]);
        }
#pragma unroll
        for (int mi = 0; mi < 4; mi++)
#pragma unroll
            for (int ni = 0; ni < 4; ni++)
                acc[mi][ni] = __builtin_amdgcn_mfma_f32_16x16x32_bf16(af[mi], bfr[ni], acc[mi][ni], 0, 0, 0);
        __syncthreads();
    }
#pragma unroll
    for (int mi = 0; mi < 4; mi++)
#pragma unroll
        for (int ni = 0; ni < 4; ni++)
#pragma unroll
            for (int r = 0; r < 4; r++) {
                long row = row0 + wm + mi * 16 + quad * 4 + r;
                int col = wn + ni * 16 + l15;
                if (col < OCH) C[row * OCH + col] = (__bf16)acc[mi][ni][r];
            }
    if (wn == 0) {
        float asv[4], adv[4];
#pragma unroll
        for (int ni = 0; ni < 4; ni++) {
            int c = ni * 16 + l15;
            bool on = c < OCH;
            asv[ni] = on ? a_s[c] : 0.f;
            adv[ni] = on ? a_d[c] : 0.f;
        }
#pragma unroll
        for (int mi = 0; mi < 4; mi++)
#pragma unroll
            for (int r = 0; r < 4; r++) {
                float vs = 0.f, vd = 0.f;
#pragma unroll
                for (int ni = 0; ni < 4; ni++) {
                    vs += acc[mi][ni][r] * asv[ni];
                    vd += acc[mi][ni][r] * adv[ni];
                }
#pragma unroll
                for (int m = 1; m <= 8; m <<= 1) {
                    vs += __shfl_xor(vs, m, 64);
                    vd += __shfl_xor(vd, m, 64);
                }
                long row = row0 + wm + mi * 16 + quad * 4 + r;
                if (l15 == 0 && row < NN) {
                    alsrc[row] = vs;
                    aldst[row] = vd;
                }
            }
    }
}

// -------- layer-1 aggregation: wave/dst; 2 edge-slots x 32 cg; pipelined ---
__global__ __launch_bounds__(256) void aggregate1(
        const int* __restrict__ offs, const int* __restrict__ csr,
        const __bf16* __restrict__ h, const float* __restrict__ alsrc,
        const float* __restrict__ aldst, const float* __restrict__ bias,
        __bf16* __restrict__ z) {
    int lane = threadIdx.x & 63, wid = threadIdx.x >> 6;
    int d = blockIdx.x * 4 + wid;
    if (d >= MPAD) return;
    int es = lane >> 5;
    int cg = lane & 31;
    if (d >= NN) {
        if (es == 0) *(uint4*)(z + (size_t)d * ICH + cg * 8) = uint4{0u, 0u, 0u, 0u};
        return;
    }
    int head = cg >> 3;
    int e0 = offs[d], e1 = offs[d + 1];
    float ald = aldst[d * HEADS + head];
    float acc[8] = {};
    float wsum = 0.f;
    int e = e0 + es;
    int sA = (e < e1) ? csr[e] : 0;
    float alA = alsrc[sA * HEADS + head];
    v8bf hvA = *(const v8bf*)(h + (size_t)sA * ICH + cg * 8);
    for (; e < e1; e += 2) {
        int en = e + 2;
        int sB = (en < e1) ? csr[en] : 0;
        float alB = alsrc[sB * HEADS + head];
        v8bf hvB = *(const v8bf*)(h + (size_t)sB * ICH + cg * 8);
        float x = alA + ald;
        x = (x > 0.f) ? x : SLOPE * x;
        float w = __expf(x);
        wsum += w;
#pragma unroll
        for (int j = 0; j < 8; j++) acc[j] += w * (float)hvA[j];
        alA = alB; hvA = hvB;
    }
#pragma unroll
    for (int j = 0; j < 8; j++) acc[j] += __shfl_down(acc[j], 32, 64);
    wsum += __shfl_down(wsum, 32, 64);
    if (es == 0) {
        float inv = 1.f / (wsum + 1e-16f);
        union { __bf16 hh[8]; uint4 u; } p;
#pragma unroll
        for (int j = 0; j < 8; j++) {
            float o = acc[j] * inv + bias[cg * 8 + j];
            o = (o > 0.f) ? o : (__expf(o) - 1.f);  // ELU
            p.hh[j] = (__bf16)o;
        }
        *(uint4*)(z + (size_t)d * ICH + cg * 8) = p.u;
    }
}

// -------- layer-2 aggregation: wave/dst; 8 edge-slots x 8 cg; compact h2 ---
__global__ __launch_bounds__(256) void aggregate2(
        const int* __restrict__ offs, const int* __restrict__ csr,
        const __bf16* __restrict__ h2, const float* __restrict__ alsrc,
        const float* __restrict__ aldst, const float* __restrict__ bias,
        float* __restrict__ out) {
    int lane = threadIdx.x & 63, wid = threadIdx.x >> 6;
    int d = blockIdx.x * 4 + wid;
    if (d >= NN) return;
    int es = lane >> 3;
    int cg = lane & 7;
    bool on = cg < 5;
    int cgc = on ? cg : 4;
    int e0 = offs[d], e1 = offs[d + 1];
    float ald = aldst[d];
    float acc[8] = {};
    float wsum = 0.f;
    int e = e0 + es;
    int sA = (e < e1) ? csr[e] : 0;
    float alA = alsrc[sA];
    v8bf hvA = *(const v8bf*)(h2 + (size_t)sA * OCH + cgc * 8);
    for (; e < e1; e += 8) {
        int en = e + 8;
        int sB = (en < e1) ? csr[en] : 0;
        float alB = alsrc[sB];
        v8bf hvB = *(const v8bf*)(h2 + (size_t)sB * OCH + cgc * 8);
        float x = alA + ald;
        x = (x > 0.f) ? x : SLOPE * x;
        float w = __expf(x);
        wsum += w;
#pragma unroll
        for (int j = 0; j < 8; j++) acc[j] += w * (float)hvA[j];
        alA = alB; hvA = hvB;
    }
#pragma unroll
    for (int m = 8; m <= 32; m <<= 1) {
#pragma unroll
        for (int j = 0; j < 8; j++) acc[j] += __shfl_xor(acc[j], m, 64);
        wsum += __shfl_xor(wsum, m, 64);
    }
    if (es == 0 && on) {
        float inv = 1.f / (wsum + 1e-16f);
#pragma unroll
        for (int j = 0; j < 8; j++)
            out[(size_t)d * OCH + cg * 8 + j] = acc[j] * inv + bias[cg * 8 + j];
    }
}

extern "C" void kernel_launch(void* const* d_in, const int* in_sizes, int n_in,
                              void* d_out, int out_size, void* d_ws, size_t ws_size,
                              hipStream_t stream) {
    const float* x   = (const float*)d_in[0];
    const int*   ei  = (const int*)d_in[1];
    const float* W1  = (const float*)d_in[2];
    const float* as1 = (const float*)d_in[3];
    const float* ad1 = (const float*)d_in[4];
    const float* b1  = (const float*)d_in[5];
    const float* W2  = (const float*)d_in[6];
    const float* as2 = (const float*)d_in[7];
    const float* ad2 = (const float*)d_in[8];
    const float* b2  = (const float*)d_in[9];
    float* out = (float*)d_out;

    char* ws = (char*)d_ws;
    size_t o = 0;
    auto alloc = [&](size_t bytes) {
        void* p = ws + o;
        o += (bytes + 255) & ~(size_t)255;
        return p;
    };
    __bf16* h1    = (__bf16*)alloc((size_t)MPAD * ICH * 2);
    __bf16* z     = (__bf16*)alloc((size_t)MPAD * ICH * 2);
    __bf16* h2    = (__bf16*)alloc((size_t)MPAD * OCH * 2);
    __bf16* W1T   = (__bf16*)alloc((size_t)256 * 256 * 2);
    __bf16* W2T   = (__bf16*)alloc((size_t)128 * 256 * 2);
    float* alsrc1 = (float*)alloc((size_t)NN * HEADS * 4);
    float* aldst1 = (float*)alloc((size_t)NN * HEADS * 4);
    float* alsrc2 = (float*)alloc((size_t)NN * 4);
    float* aldst2 = (float*)alloc((size_t)NN * 4);
    int*   deg    = (int*)alloc((size_t)NN * 4);
    int*   offs   = (int*)alloc((size_t)(NN + 1) * 4);
    int*   csr    = (int*)alloc((size_t)ETOT * 4);
    int*   rank   = (int*)alloc((size_t)ETOT * 4);
    int*   bsum   = (int*)alloc((size_t)SCAN_B * 4);

    const int* srcArr = ei;
    const int* dstArr = ei + NE;

    // deg must be zero before prep's hist branch
    hipMemsetAsync(deg, 0, (size_t)NN * 4, stream);

    // prep: transW || hist (task-parallel block ranges)
    prep_kernel<<<384 + HB, 256, 0, stream>>>(W1, W2, W1T, W2T, dstArr, deg, rank);
    blocksum_kernel<<<SCAN_B, 256, 0, stream>>>(deg, bsum);
    scan_final<<<SCAN_B, 256, 0, stream>>>(deg, bsum, offs);

    // layer-1 GEMM || CSR scatter (independent; co-scheduled)
    gemm1_scatter<<<GB1 + HB, 256, 0, stream>>>(x, W1T, h1, as1, ad1, alsrc1, aldst1,
                                                srcArr, dstArr, offs, rank, csr);
    aggregate1<<<MPAD / 4, 256, 0, stream>>>(offs, csr, h1, alsrc1, aldst1, b1, z);

    // Layer 2
    gemm2_fused<<<dim3(1, MPAD / 128), 256, 0, stream>>>(z, W2T, h2, as2, ad2, alsrc2, aldst2);
    aggregate2<<<(NN + 3) / 4, 256, 0, stream>>>(offs, csr, h2, alsrc2, aldst2, b2, out);
}

// Round 10
// 279.926 us; speedup vs baseline: 3.3257x; 1.0808x over previous
//
#include <hip/hip_runtime.h>

#define NN 50000
#define MPAD 50048   // 391 * 128 = 782 * 64
#define ICH 256
#define HID 64
#define HEADS 4
#define OCH 40
#define NE 800000
#define ETOT (NE + NN)
#define SLOPE 0.2f
#define LDP 40       // padded LDS row stride (bf16 elems): 32 data + 8 pad
#define SCAN_B 196   // 196 * 256 = 50176 >= NN
#define HB ((ETOT + 255) / 256)

typedef __bf16 v8bf __attribute__((ext_vector_type(8)));
typedef float v4f __attribute__((ext_vector_type(4)));

// ---- prep: blocks [0,384) transpose W1/W2 to bf16; blocks [384, ...) hist --
// deg must be zeroed (memset) BEFORE this kernel.
__global__ __launch_bounds__(256) void prep_kernel(
        const float* __restrict__ W1, const float* __restrict__ W2,
        __bf16* __restrict__ W1T, __bf16* __restrict__ W2T,
        const int* __restrict__ dstArr, int* __restrict__ deg,
        int* __restrict__ rank) {
    int blk = blockIdx.x;
    if (blk < 384) {
        int i = blk * 256 + threadIdx.x;  // 0..98303
        if (i < 65536) {
            int n = i >> 8, k = i & 255;
            W1T[n * 256 + k] = (__bf16)W1[k * 256 + n];
        } else {
            int j = i - 65536;  // 0..32767
            int n = j >> 8, k = j & 255;
            W2T[n * 256 + k] = (n < OCH) ? (__bf16)W2[k * OCH + n] : (__bf16)0.f;
        }
    } else {
        int i = (blk - 384) * 256 + threadIdx.x;
        if (i < ETOT) {
            int d = (i < NE) ? dstArr[i] : (i - NE);
            rank[i] = atomicAdd(&deg[d], 1);
        }
    }
}

__global__ __launch_bounds__(256) void blocksum_kernel(const int* __restrict__ deg,
                                                       int* __restrict__ bsum) {
    __shared__ int wsum[4];
    int i = blockIdx.x * 256 + threadIdx.x;
    int v = (i < NN) ? deg[i] : 0;
#pragma unroll
    for (int m = 1; m <= 32; m <<= 1) v += __shfl_xor(v, m, 64);
    if ((threadIdx.x & 63) == 0) wsum[threadIdx.x >> 6] = v;
    __syncthreads();
    if (threadIdx.x == 0) bsum[blockIdx.x] = wsum[0] + wsum[1] + wsum[2] + wsum[3];
}

__global__ __launch_bounds__(256) void scan_final(const int* __restrict__ deg,
                                                  const int* __restrict__ bsum,
                                                  int* __restrict__ offs) {
    __shared__ int wsum[4];
    int t = threadIdx.x;
    int lane = t & 63, w = t >> 6;
    int pv = (t < blockIdx.x) ? bsum[t] : 0;  // blockIdx.x <= 195 < 256
#pragma unroll
    for (int m = 1; m <= 32; m <<= 1) pv += __shfl_xor(pv, m, 64);
    if (lane == 0) wsum[w] = pv;
    __syncthreads();
    int base = wsum[0] + wsum[1] + wsum[2] + wsum[3];
    __syncthreads();
    int i = blockIdx.x * 256 + t;
    int v = (i < NN) ? deg[i] : 0;
    int x = v;
#pragma unroll
    for (int off = 1; off < 64; off <<= 1) {
        int tt = __shfl_up(x, off, 64);
        if (lane >= off) x += tt;
    }
    if (lane == 63) wsum[w] = x;
    __syncthreads();
    int wbase = 0;
    for (int k = 0; k < w; k++) wbase += wsum[k];
    int excl = base + wbase + x - v;
    if (i < NN) {
        offs[i] = excl;
        if (i == NN - 1) offs[NN] = excl + v;
    }
}

__global__ void scatter_kernel(const int* __restrict__ srcArr, const int* __restrict__ dstArr,
                               const int* __restrict__ offs, const int* __restrict__ rank,
                               int* __restrict__ csr) {
    int i = blockIdx.x * blockDim.x + threadIdx.x;
    if (i < ETOT) {
        int s, d;
        if (i < NE) {
            s = srcArr[i];
            d = dstArr[i];
        } else {
            s = d = i - NE;
        }
        csr[offs[d] + rank[i]] = s;
    }
}

// ---- layer-1 GEMM v3: 64-row x 256-col tiles, grid=782 (high occupancy),
//      x read once, fp32->bf16 in-register staging, al1 epilogue ------------
__global__ __launch_bounds__(256) void gemm1_fused(
        const float* __restrict__ X, const __bf16* __restrict__ B,
        __bf16* __restrict__ C, const float* __restrict__ a_s,
        const float* __restrict__ a_d, float* __restrict__ alsrc,
        float* __restrict__ aldst) {
    __shared__ __bf16 As[64 * LDP];
    __shared__ __bf16 Bs[256 * LDP];
    int tid = threadIdx.x;
    int lane = tid & 63, wid = tid >> 6;
    int quad = lane >> 4, l15 = lane & 15;
    int wn = wid * 64;               // each wave: 64 rows x 64 cols (one head)
    long row0 = (long)blockIdx.x * 64;
    v4f acc[4][4] = {};
    for (int k0 = 0; k0 < 256; k0 += 32) {
        {   // stage A: 64 rows x 32 k, fp32 -> bf16, one uint4 per thread
            int r = tid >> 2, q = tid & 3;
            long row = row0 + r;
            union { __bf16 hh[8]; uint4 u; } pk;
            if (row < NN) {
                const float4* p = (const float4*)(X + row * ICH + k0 + q * 8);
                float4 f0 = p[0], f1 = p[1];
                pk.hh[0] = (__bf16)f0.x; pk.hh[1] = (__bf16)f0.y;
                pk.hh[2] = (__bf16)f0.z; pk.hh[3] = (__bf16)f0.w;
                pk.hh[4] = (__bf16)f1.x; pk.hh[5] = (__bf16)f1.y;
                pk.hh[6] = (__bf16)f1.z; pk.hh[7] = (__bf16)f1.w;
            } else {
                pk.u = uint4{0u, 0u, 0u, 0u};
            }
            *(uint4*)(&As[r * LDP + q * 8]) = pk.u;
        }
#pragma unroll
        for (int t = 0; t < 4; t++) {  // stage B: 256 cols x 32 k
            int i = tid + t * 256;
            int r = i >> 2, q = i & 3;
            *(uint4*)(&Bs[r * LDP + q * 8]) = *(const uint4*)(B + (size_t)r * 256 + k0 + q * 8);
        }
        __syncthreads();
        v8bf af[4], bfr[4];
#pragma unroll
        for (int t = 0; t < 4; t++) {
            af[t]  = *(const v8bf*)(&As[(t * 16 + l15) * LDP + quad * 8]);
            bfr[t] = *(const v8bf*)(&Bs[(wn + t * 16 + l15) * LDP + quad * 8]);
        }
#pragma unroll
        for (int mi = 0; mi < 4; mi++)
#pragma unroll
            for (int ni = 0; ni < 4; ni++)
                acc[mi][ni] = __builtin_amdgcn_mfma_f32_16x16x32_bf16(af[mi], bfr[ni], acc[mi][ni], 0, 0, 0);
        __syncthreads();
    }
    // C write
#pragma unroll
    for (int mi = 0; mi < 4; mi++)
#pragma unroll
        for (int ni = 0; ni < 4; ni++)
#pragma unroll
            for (int r = 0; r < 4; r++) {
                long row = row0 + mi * 16 + quad * 4 + r;
                C[row * ICH + wn + ni * 16 + l15] = (__bf16)acc[mi][ni][r];
            }
    // fused al1: this wave's 64 cols are exactly one head
    int head = wn >> 6;
    float asv[4], adv[4];
#pragma unroll
    for (int ni = 0; ni < 4; ni++) {
        int cc = wn + ni * 16 + l15;
        asv[ni] = a_s[cc];
        adv[ni] = a_d[cc];
    }
#pragma unroll
    for (int mi = 0; mi < 4; mi++)
#pragma unroll
        for (int r = 0; r < 4; r++) {
            float vs = 0.f, vd = 0.f;
#pragma unroll
            for (int ni = 0; ni < 4; ni++) {
                vs += acc[mi][ni][r] * asv[ni];
                vd += acc[mi][ni][r] * adv[ni];
            }
#pragma unroll
            for (int m = 1; m <= 8; m <<= 1) {
                vs += __shfl_xor(vs, m, 64);
                vd += __shfl_xor(vd, m, 64);
            }
            long row = row0 + mi * 16 + quad * 4 + r;
            if (l15 == 0 && row < NN) {
                alsrc[row * HEADS + head] = vs;
                aldst[row * HEADS + head] = vd;
            }
        }
}

// ---- layer-2 GEMM v3: 64-row x 128-col tiles, grid=782; compact 40-col C;
//      al2 epilogue --------------------------------------------------------
__global__ __launch_bounds__(256) void gemm2_fused(
        const __bf16* __restrict__ A, const __bf16* __restrict__ B,
        __bf16* __restrict__ C, const float* __restrict__ a_s,
        const float* __restrict__ a_d, float* __restrict__ alsrc,
        float* __restrict__ aldst) {
    __shared__ __bf16 As[64 * LDP];
    __shared__ __bf16 Bs[128 * LDP];
    int tid = threadIdx.x;
    int lane = tid & 63, wid = tid >> 6;
    int quad = lane >> 4, l15 = lane & 15;
    int wm = (wid >> 1) * 32, wn = (wid & 1) * 64;  // wave: 32 rows x 64 cols
    long row0 = (long)blockIdx.x * 64;
    v4f acc[2][4] = {};
    for (int k0 = 0; k0 < 256; k0 += 32) {
        {   // stage A: 64 rows x 32 k (bf16 passthrough; z has MPAD rows)
            int r = tid >> 2, q = tid & 3;
            *(uint4*)(&As[r * LDP + q * 8]) = *(const uint4*)(A + (row0 + r) * 256 + k0 + q * 8);
        }
#pragma unroll
        for (int t = 0; t < 2; t++) {  // stage B: 128 cols x 32 k
            int i = tid + t * 256;
            int r = i >> 2, q = i & 3;
            *(uint4*)(&Bs[r * LDP + q * 8]) = *(const uint4*)(B + (size_t)r * 256 + k0 + q * 8);
        }
        __syncthreads();
        v8bf af[2], bfr[4];
#pragma unroll
        for (int t = 0; t < 2; t++)
            af[t] = *(const v8bf*)(&As[(wm + t * 16 + l15) * LDP + quad * 8]);
#pragma unroll
        for (int t = 0; t < 4; t++)
            bfr[t] = *(const v8bf*)(&Bs[(wn + t * 16 + l15) * LDP + quad * 8]);
#pragma unroll
        for (int mi = 0; mi < 2; mi++)
#pragma unroll
            for (int ni = 0; ni < 4; ni++)
                acc[mi][ni] = __builtin_amdgcn_mfma_f32_16x16x32_bf16(af[mi], bfr[ni], acc[mi][ni], 0, 0, 0);
        __syncthreads();
    }
#pragma unroll
    for (int mi = 0; mi < 2; mi++)
#pragma unroll
        for (int ni = 0; ni < 4; ni++)
#pragma unroll
            for (int r = 0; r < 4; r++) {
                long row = row0 + wm + mi * 16 + quad * 4 + r;
                int col = wn + ni * 16 + l15;
                if (col < OCH) C[row * OCH + col] = (__bf16)acc[mi][ni][r];
            }
    if (wn == 0) {  // al2: cols 0..63 wave holds all 40 valid cols
        float asv[4], adv[4];
#pragma unroll
        for (int ni = 0; ni < 4; ni++) {
            int c = ni * 16 + l15;
            bool on = c < OCH;
            asv[ni] = on ? a_s[c] : 0.f;
            adv[ni] = on ? a_d[c] : 0.f;
        }
#pragma unroll
        for (int mi = 0; mi < 2; mi++)
#pragma unroll
            for (int r = 0; r < 4; r++) {
                float vs = 0.f, vd = 0.f;
#pragma unroll
                for (int ni = 0; ni < 4; ni++) {
                    vs += acc[mi][ni][r] * asv[ni];
                    vd += acc[mi][ni][r] * adv[ni];
                }
#pragma unroll
                for (int m = 1; m <= 8; m <<= 1) {
                    vs += __shfl_xor(vs, m, 64);
                    vd += __shfl_xor(vd, m, 64);
                }
                long row = row0 + wm + mi * 16 + quad * 4 + r;
                if (l15 == 0 && row < NN) {
                    alsrc[row] = vs;
                    aldst[row] = vd;
                }
            }
    }
}

// -------- layer-1 aggregation: wave/dst; 2 edge-slots x 32 cg; pipelined ---
__global__ __launch_bounds__(256) void aggregate1(
        const int* __restrict__ offs, const int* __restrict__ csr,
        const __bf16* __restrict__ h, const float* __restrict__ alsrc,
        const float* __restrict__ aldst, const float* __restrict__ bias,
        __bf16* __restrict__ z) {
    int lane = threadIdx.x & 63, wid = threadIdx.x >> 6;
    int d = blockIdx.x * 4 + wid;
    if (d >= MPAD) return;
    int es = lane >> 5;
    int cg = lane & 31;
    if (d >= NN) {
        if (es == 0) *(uint4*)(z + (size_t)d * ICH + cg * 8) = uint4{0u, 0u, 0u, 0u};
        return;
    }
    int head = cg >> 3;
    int e0 = offs[d], e1 = offs[d + 1];
    float ald = aldst[d * HEADS + head];
    float acc[8] = {};
    float wsum = 0.f;
    int e = e0 + es;
    int sA = (e < e1) ? csr[e] : 0;
    float alA = alsrc[sA * HEADS + head];
    v8bf hvA = *(const v8bf*)(h + (size_t)sA * ICH + cg * 8);
    for (; e < e1; e += 2) {
        int en = e + 2;
        int sB = (en < e1) ? csr[en] : 0;
        float alB = alsrc[sB * HEADS + head];
        v8bf hvB = *(const v8bf*)(h + (size_t)sB * ICH + cg * 8);
        float x = alA + ald;
        x = (x > 0.f) ? x : SLOPE * x;
        float w = __expf(x);
        wsum += w;
#pragma unroll
        for (int j = 0; j < 8; j++) acc[j] += w * (float)hvA[j];
        alA = alB; hvA = hvB;
    }
#pragma unroll
    for (int j = 0; j < 8; j++) acc[j] += __shfl_down(acc[j], 32, 64);
    wsum += __shfl_down(wsum, 32, 64);
    if (es == 0) {
        float inv = 1.f / (wsum + 1e-16f);
        union { __bf16 hh[8]; uint4 u; } p;
#pragma unroll
        for (int j = 0; j < 8; j++) {
            float o = acc[j] * inv + bias[cg * 8 + j];
            o = (o > 0.f) ? o : (__expf(o) - 1.f);  // ELU
            p.hh[j] = (__bf16)o;
        }
        *(uint4*)(z + (size_t)d * ICH + cg * 8) = p.u;
    }
}

// -------- layer-2 aggregation: wave/dst; 8 edge-slots x 8 cg; compact h2 ---
__global__ __launch_bounds__(256) void aggregate2(
        const int* __restrict__ offs, const int* __restrict__ csr,
        const __bf16* __restrict__ h2, const float* __restrict__ alsrc,
        const float* __restrict__ aldst, const float* __restrict__ bias,
        float* __restrict__ out) {
    int lane = threadIdx.x & 63, wid = threadIdx.x >> 6;
    int d = blockIdx.x * 4 + wid;
    if (d >= NN) return;
    int es = lane >> 3;
    int cg = lane & 7;
    bool on = cg < 5;
    int cgc = on ? cg : 4;
    int e0 = offs[d], e1 = offs[d + 1];
    float ald = aldst[d];
    float acc[8] = {};
    float wsum = 0.f;
    int e = e0 + es;
    int sA = (e < e1) ? csr[e] : 0;
    float alA = alsrc[sA];
    v8bf hvA = *(const v8bf*)(h2 + (size_t)sA * OCH + cgc * 8);
    for (; e < e1; e += 8) {
        int en = e + 8;
        int sB = (en < e1) ? csr[en] : 0;
        float alB = alsrc[sB];
        v8bf hvB = *(const v8bf*)(h2 + (size_t)sB * OCH + cgc * 8);
        float x = alA + ald;
        x = (x > 0.f) ? x : SLOPE * x;
        float w = __expf(x);
        wsum += w;
#pragma unroll
        for (int j = 0; j < 8; j++) acc[j] += w * (float)hvA[j];
        alA = alB; hvA = hvB;
    }
#pragma unroll
    for (int m = 8; m <= 32; m <<= 1) {
#pragma unroll
        for (int j = 0; j < 8; j++) acc[j] += __shfl_xor(acc[j], m, 64);
        wsum += __shfl_xor(wsum, m, 64);
    }
    if (es == 0 && on) {
        float inv = 1.f / (wsum + 1e-16f);
#pragma unroll
        for (int j = 0; j < 8; j++)
            out[(size_t)d * OCH + cg * 8 + j] = acc[j] * inv + bias[cg * 8 + j];
    }
}

extern "C" void kernel_launch(void* const* d_in, const int* in_sizes, int n_in,
                              void* d_out, int out_size, void* d_ws, size_t ws_size,
                              hipStream_t stream) {
    const float* x   = (const float*)d_in[0];
    const int*   ei  = (const int*)d_in[1];
    const float* W1  = (const float*)d_in[2];
    const float* as1 = (const float*)d_in[3];
    const float* ad1 = (const float*)d_in[4];
    const float* b1  = (const float*)d_in[5];
    const float* W2  = (const float*)d_in[6];
    const float* as2 = (const float*)d_in[7];
    const float* ad2 = (const float*)d_in[8];
    const float* b2  = (const float*)d_in[9];
    float* out = (float*)d_out;

    char* ws = (char*)d_ws;
    size_t o = 0;
    auto alloc = [&](size_t bytes) {
        void* p = ws + o;
        o += (bytes + 255) & ~(size_t)255;
        return p;
    };
    __bf16* h1    = (__bf16*)alloc((size_t)MPAD * ICH * 2);
    __bf16* z     = (__bf16*)alloc((size_t)MPAD * ICH * 2);
    __bf16* h2    = (__bf16*)alloc((size_t)MPAD * OCH * 2);
    __bf16* W1T   = (__bf16*)alloc((size_t)256 * 256 * 2);
    __bf16* W2T   = (__bf16*)alloc((size_t)128 * 256 * 2);
    float* alsrc1 = (float*)alloc((size_t)NN * HEADS * 4);
    float* aldst1 = (float*)alloc((size_t)NN * HEADS * 4);
    float* alsrc2 = (float*)alloc((size_t)NN * 4);
    float* aldst2 = (float*)alloc((size_t)NN * 4);
    int*   deg    = (int*)alloc((size_t)NN * 4);
    int*   offs   = (int*)alloc((size_t)(NN + 1) * 4);
    int*   csr    = (int*)alloc((size_t)ETOT * 4);
    int*   rank   = (int*)alloc((size_t)ETOT * 4);
    int*   bsum   = (int*)alloc((size_t)SCAN_B * 4);

    const int* srcArr = ei;
    const int* dstArr = ei + NE;

    // deg must be zero before prep's hist branch
    hipMemsetAsync(deg, 0, (size_t)NN * 4, stream);

    // prep: transW || hist (task-parallel block ranges)
    prep_kernel<<<384 + HB, 256, 0, stream>>>(W1, W2, W1T, W2T, dstArr, deg, rank);
    blocksum_kernel<<<SCAN_B, 256, 0, stream>>>(deg, bsum);
    scan_final<<<SCAN_B, 256, 0, stream>>>(deg, bsum, offs);
    scatter_kernel<<<HB, 256, 0, stream>>>(srcArr, dstArr, offs, rank, csr);

    // Layer 1 (64-row tiles, grid 782, x read once, al1 fused)
    gemm1_fused<<<MPAD / 64, 256, 0, stream>>>(x, W1T, h1, as1, ad1, alsrc1, aldst1);
    aggregate1<<<MPAD / 4, 256, 0, stream>>>(offs, csr, h1, alsrc1, aldst1, b1, z);

    // Layer 2 (64-row tiles, grid 782, compact h2, al2 fused)
    gemm2_fused<<<MPAD / 64, 256, 0, stream>>>(z, W2T, h2, as2, ad2, alsrc2, aldst2);
    aggregate2<<<(NN + 3) / 4, 256, 0, stream>>>(offs, csr, h2, alsrc2, aldst2, b2, out);
}